// Round 1
// baseline (727.089 us; speedup 1.0000x reference)
//
#include <hip/hip_runtime.h>
#include <math.h>

// Sizes (compile-time): B=4, S=1024, D=768, H=12, E=64, 3D=2304
// Workspace layout (floats):
//   qkv    @ 0          : B*S*3D      = 9,437,184
//   scores @ 9,437,184  : B*H*S*S    = 50,331,648   (mixed/softmaxed in place)
//   ctx    @ 59,768,832 : B*H*S*E    = 3,145,728
// Total 251,658,240 bytes = 240 MiB of d_ws.

#define BM 64
#define BN 64
#define BK 16
#define LDT 68  // BM + 4 pad: keeps float4 alignment, 2-way LDS conflict max (free)

// ---------------- K1: QKV projection ----------------
// qkv[m][f] = sum_d x[m][d] * Wqkv[f][d];  M=4096, N=2304, K=768
__global__ __launch_bounds__(256) void k_qkv(const float* __restrict__ x,
                                             const float* __restrict__ W,
                                             float* __restrict__ out) {
  __shared__ float As[BK][LDT];
  __shared__ float Bs[BK][LDT];
  const int t  = threadIdx.x;
  const int n0 = blockIdx.x * BN;
  const int m0 = blockIdx.y * BM;
  const int ri = t >> 2;          // tile row 0..63
  const int k4 = (t & 3) * 4;     // k sub-offset 0,4,8,12
  const int tx = t & 15, ty = t >> 4;
  float acc[4][4] = {};
  for (int k0 = 0; k0 < 768; k0 += BK) {
    float4 a = *(const float4*)&x[(size_t)(m0 + ri) * 768 + k0 + k4];
    float4 b = *(const float4*)&W[(size_t)(n0 + ri) * 768 + k0 + k4];
    __syncthreads();
    As[k4 + 0][ri] = a.x; As[k4 + 1][ri] = a.y; As[k4 + 2][ri] = a.z; As[k4 + 3][ri] = a.w;
    Bs[k4 + 0][ri] = b.x; Bs[k4 + 1][ri] = b.y; Bs[k4 + 2][ri] = b.z; Bs[k4 + 3][ri] = b.w;
    __syncthreads();
#pragma unroll
    for (int kk = 0; kk < BK; ++kk) {
      float4 av = *(const float4*)&As[kk][ty * 4];
      float4 bv = *(const float4*)&Bs[kk][tx * 4];
      float aa[4] = {av.x, av.y, av.z, av.w};
      float bb[4] = {bv.x, bv.y, bv.z, bv.w};
#pragma unroll
      for (int i = 0; i < 4; ++i)
#pragma unroll
        for (int j = 0; j < 4; ++j) acc[i][j] = fmaf(aa[i], bb[j], acc[i][j]);
    }
  }
#pragma unroll
  for (int i = 0; i < 4; ++i) {
    float4 c = {acc[i][0], acc[i][1], acc[i][2], acc[i][3]};
    *(float4*)&out[(size_t)(m0 + ty * 4 + i) * 2304 + n0 + tx * 4] = c;
  }
}

// ---------------- K2: scores = Q K^T per (b,h) ----------------
// M=N=1024, K=64, lda=ldb=2304 (strided into qkv buffer)
__global__ __launch_bounds__(256) void k_qk(const float* __restrict__ qkv,
                                            float* __restrict__ scores) {
  __shared__ float As[BK][LDT];
  __shared__ float Bs[BK][LDT];
  const int t  = threadIdx.x;
  const int bh = blockIdx.z;
  const int b  = bh / 12, h = bh % 12;
  const float* Q  = qkv + (size_t)b * 1024 * 2304 + h * 64;        // + m*2304 + e
  const float* Kp = Q + 768;                                        // K block
  float* C = scores + (size_t)bh * 1024 * 1024;
  const int n0 = blockIdx.x * BN;
  const int m0 = blockIdx.y * BM;
  const int ri = t >> 2;
  const int k4 = (t & 3) * 4;
  const int tx = t & 15, ty = t >> 4;
  float acc[4][4] = {};
  for (int k0 = 0; k0 < 64; k0 += BK) {
    float4 a = *(const float4*)&Q [(size_t)(m0 + ri) * 2304 + k0 + k4];
    float4 b = *(const float4*)&Kp[(size_t)(n0 + ri) * 2304 + k0 + k4];
    __syncthreads();
    As[k4 + 0][ri] = a.x; As[k4 + 1][ri] = a.y; As[k4 + 2][ri] = a.z; As[k4 + 3][ri] = a.w;
    Bs[k4 + 0][ri] = b.x; Bs[k4 + 1][ri] = b.y; Bs[k4 + 2][ri] = b.z; Bs[k4 + 3][ri] = b.w;
    __syncthreads();
#pragma unroll
    for (int kk = 0; kk < BK; ++kk) {
      float4 av = *(const float4*)&As[kk][ty * 4];
      float4 bv = *(const float4*)&Bs[kk][tx * 4];
      float aa[4] = {av.x, av.y, av.z, av.w};
      float bb[4] = {bv.x, bv.y, bv.z, bv.w};
#pragma unroll
      for (int i = 0; i < 4; ++i)
#pragma unroll
        for (int j = 0; j < 4; ++j) acc[i][j] = fmaf(aa[i], bb[j], acc[i][j]);
    }
  }
#pragma unroll
  for (int i = 0; i < 4; ++i) {
    float4 c = {acc[i][0], acc[i][1], acc[i][2], acc[i][3]};
    *(float4*)&C[(size_t)(m0 + ty * 4 + i) * 1024 + n0 + tx * 4] = c;
  }
}

// ---------------- K3: mix1(+bl) -> softmax -> mix2(+bw), in place ----------------
// One workgroup per (b,q). 12 rows x 1024 cols live in LDS.
__global__ __launch_bounds__(256) void k_mix(float* __restrict__ scores,
                                             const float* __restrict__ Wl,
                                             const float* __restrict__ bl,
                                             const float* __restrict__ Ww,
                                             const float* __restrict__ bw) {
  __shared__ float rows[12][1024];
  __shared__ float wl_s[144], ww_s[144], bl_s[12], bw_s[12];
  const int t  = threadIdx.x;
  const int bq = blockIdx.x;
  const int b  = bq >> 10, q = bq & 1023;
  if (t < 144) { wl_s[t] = Wl[t]; ww_s[t] = Ww[t]; }
  if (t < 12)  { bl_s[t] = bl[t]; bw_s[t] = bw[t]; }
  float* base = scores + ((size_t)b * 12 * 1024 + q) * 1024;  // + h*1024*1024 + k
#pragma unroll
  for (int h = 0; h < 12; ++h) {
    const float* src = base + (size_t)h * 1024 * 1024;
    for (int k = t; k < 1024; k += 256) rows[h][k] = src[k];
  }
  __syncthreads();
  // mix1: logits[g][k] = bl[g] + sum_h Wl[g,h] * raw[h][k]
  for (int k = t; k < 1024; k += 256) {
    float raw[12];
#pragma unroll
    for (int h = 0; h < 12; ++h) raw[h] = rows[h][k];
#pragma unroll
    for (int g = 0; g < 12; ++g) {
      float m = bl_s[g];
#pragma unroll
      for (int h = 0; h < 12; ++h) m = fmaf(wl_s[g * 12 + h], raw[h], m);
      rows[g][k] = m;
    }
  }
  __syncthreads();
  // softmax per row over k; wave w handles rows 3w..3w+2 (wave-local shuffles only)
  const int wave = t >> 6, lane = t & 63;
  for (int g = wave * 3; g < wave * 3 + 3; ++g) {
    float m = -INFINITY;
    for (int k = lane; k < 1024; k += 64) m = fmaxf(m, rows[g][k]);
#pragma unroll
    for (int off = 32; off > 0; off >>= 1) m = fmaxf(m, __shfl_xor(m, off));
    float ssum = 0.f;
    for (int k = lane; k < 1024; k += 64) {
      float e = __expf(rows[g][k] - m);
      rows[g][k] = e;
      ssum += e;
    }
#pragma unroll
    for (int off = 32; off > 0; off >>= 1) ssum += __shfl_xor(ssum, off);
    const float inv = 1.0f / ssum;
    for (int k = lane; k < 1024; k += 64) rows[g][k] *= inv;
  }
  __syncthreads();
  // mix2: probs2[g][k] = bw[g] + sum_h Ww[g,h] * probs[h][k]
  for (int k = t; k < 1024; k += 256) {
    float p[12];
#pragma unroll
    for (int h = 0; h < 12; ++h) p[h] = rows[h][k];
#pragma unroll
    for (int g = 0; g < 12; ++g) {
      float m = bw_s[g];
#pragma unroll
      for (int h = 0; h < 12; ++h) m = fmaf(ww_s[g * 12 + h], p[h], m);
      rows[g][k] = m;
    }
  }
  __syncthreads();
#pragma unroll
  for (int h = 0; h < 12; ++h) {
    float* dst = base + (size_t)h * 1024 * 1024;
    for (int k = t; k < 1024; k += 256) dst[k] = rows[h][k];
  }
}

// ---------------- K4: ctx = P2 @ V per (b,h) ----------------
// M=1024, N=64(=E, single tile), K=1024. NN GEMM (V rows strided 2304).
__global__ __launch_bounds__(256) void k_pv(const float* __restrict__ qkv,
                                            const float* __restrict__ scores,
                                            float* __restrict__ ctx) {
  __shared__ float As[BK][LDT];
  __shared__ float Bs[BK][LDT];   // Bs[kk][e] — not transposed
  const int t  = threadIdx.x;
  const int bh = blockIdx.y;
  const int b  = bh / 12, h = bh % 12;
  const float* P = scores + (size_t)bh * 1024 * 1024;
  const float* V = qkv + (size_t)b * 1024 * 2304 + 1536 + h * 64;  // + k*2304 + e
  float* C = ctx + (size_t)bh * 1024 * 64;
  const int m0 = blockIdx.x * BM;
  const int ri = t >> 2;
  const int k4 = (t & 3) * 4;
  const int vk = t >> 4;          // B-tile row 0..15
  const int vc = (t & 15) * 4;    // B-tile col group
  const int tx = t & 15, ty = t >> 4;
  float acc[4][4] = {};
  for (int k0 = 0; k0 < 1024; k0 += BK) {
    float4 a  = *(const float4*)&P[(size_t)(m0 + ri) * 1024 + k0 + k4];
    float4 b4 = *(const float4*)&V[(size_t)(k0 + vk) * 2304 + vc];
    __syncthreads();
    As[k4 + 0][ri] = a.x; As[k4 + 1][ri] = a.y; As[k4 + 2][ri] = a.z; As[k4 + 3][ri] = a.w;
    *(float4*)&Bs[vk][vc] = b4;
    __syncthreads();
#pragma unroll
    for (int kk = 0; kk < BK; ++kk) {
      float4 av = *(const float4*)&As[kk][ty * 4];
      float4 bv = *(const float4*)&Bs[kk][tx * 4];
      float aa[4] = {av.x, av.y, av.z, av.w};
      float bb[4] = {bv.x, bv.y, bv.z, bv.w};
#pragma unroll
      for (int i = 0; i < 4; ++i)
#pragma unroll
        for (int j = 0; j < 4; ++j) acc[i][j] = fmaf(aa[i], bb[j], acc[i][j]);
    }
  }
#pragma unroll
  for (int i = 0; i < 4; ++i) {
    float4 c = {acc[i][0], acc[i][1], acc[i][2], acc[i][3]};
    *(float4*)&C[(size_t)(m0 + ty * 4 + i) * 64 + tx * 4] = c;
  }
}

// ---------------- K5: out = ctx_t @ Wp^T + bp ----------------
// M=4096, N=768, K=768; A gathered: A[m=(b,s)][d=(h,e)] = ctx[b,h,s,e]
__global__ __launch_bounds__(256) void k_oproj(const float* __restrict__ ctx,
                                               const float* __restrict__ Wp,
                                               const float* __restrict__ bp,
                                               float* __restrict__ out) {
  __shared__ float As[BK][LDT];
  __shared__ float Bs[BK][LDT];
  const int t  = threadIdx.x;
  const int n0 = blockIdx.x * BN;
  const int m0 = blockIdx.y * BM;
  const int ri = t >> 2;
  const int k4 = (t & 3) * 4;
  const int tx = t & 15, ty = t >> 4;
  const int m  = m0 + ri;
  const int b  = m >> 10, s = m & 1023;
  float acc[4][4] = {};
  for (int k0 = 0; k0 < 768; k0 += BK) {
    const int d0 = k0 + k4;
    const int h = d0 >> 6, e = d0 & 63;    // 4-wide chunk never crosses an h boundary
    float4 a = *(const float4*)&ctx[((size_t)(b * 12 + h) * 1024 + s) * 64 + e];
    float4 bvv = *(const float4*)&Wp[(size_t)(n0 + ri) * 768 + d0];
    __syncthreads();
    As[k4 + 0][ri] = a.x; As[k4 + 1][ri] = a.y; As[k4 + 2][ri] = a.z; As[k4 + 3][ri] = a.w;
    Bs[k4 + 0][ri] = bvv.x; Bs[k4 + 1][ri] = bvv.y; Bs[k4 + 2][ri] = bvv.z; Bs[k4 + 3][ri] = bvv.w;
    __syncthreads();
#pragma unroll
    for (int kk = 0; kk < BK; ++kk) {
      float4 av = *(const float4*)&As[kk][ty * 4];
      float4 bv = *(const float4*)&Bs[kk][tx * 4];
      float aa[4] = {av.x, av.y, av.z, av.w};
      float bb[4] = {bv.x, bv.y, bv.z, bv.w};
#pragma unroll
      for (int i = 0; i < 4; ++i)
#pragma unroll
        for (int j = 0; j < 4; ++j) acc[i][j] = fmaf(aa[i], bb[j], acc[i][j]);
    }
  }
  float4 bias = *(const float4*)&bp[n0 + tx * 4];
#pragma unroll
  for (int i = 0; i < 4; ++i) {
    float4 c = {acc[i][0] + bias.x, acc[i][1] + bias.y, acc[i][2] + bias.z, acc[i][3] + bias.w};
    *(float4*)&out[(size_t)(m0 + ty * 4 + i) * 768 + n0 + tx * 4] = c;
  }
}

extern "C" void kernel_launch(void* const* d_in, const int* in_sizes, int n_in,
                              void* d_out, int out_size, void* d_ws, size_t ws_size,
                              hipStream_t stream) {
  const float* x    = (const float*)d_in[0];
  const float* Wqkv = (const float*)d_in[1];
  const float* Wl   = (const float*)d_in[2];
  const float* bl   = (const float*)d_in[3];
  const float* Ww   = (const float*)d_in[4];
  const float* bw   = (const float*)d_in[5];
  const float* Wp   = (const float*)d_in[6];
  const float* bp   = (const float*)d_in[7];
  float* out = (float*)d_out;

  float* ws     = (float*)d_ws;
  float* qkv    = ws;                 // 9,437,184 floats
  float* scores = ws + 9437184ull;    // 50,331,648 floats
  float* ctx    = ws + 59768832ull;   // 3,145,728 floats
  // requires ws_size >= 251,658,240 bytes (240 MiB)

  hipLaunchKernelGGL(k_qkv,   dim3(36, 64),     dim3(256), 0, stream, x, Wqkv, qkv);
  hipLaunchKernelGGL(k_qk,    dim3(16, 16, 48), dim3(256), 0, stream, qkv, scores);
  hipLaunchKernelGGL(k_mix,   dim3(4096),       dim3(256), 0, stream, scores, Wl, bl, Ww, bw);
  hipLaunchKernelGGL(k_pv,    dim3(16, 48),     dim3(256), 0, stream, qkv, scores, ctx);
  hipLaunchKernelGGL(k_oproj, dim3(12, 64),     dim3(256), 0, stream, ctx, Wp, bp, out);
}

// Round 3
// 386.150 us; speedup vs baseline: 1.8829x; 1.8829x over previous
//
#include <hip/hip_runtime.h>
#include <math.h>

// B=4, S=1024, D=768, H=12, E=64, 3D=2304
// Workspace layout (bytes), total 251,658,240 (= 240 MiB, same as round 1):
//   scores fp32 : 201,326,592 @ 0            (mix/softmax in place)
//   qkv_hi bf16 :  18,874,368 @ 201,326,592
//   qkv_lo bf16 :  18,874,368 @ 220,200,960
//   vT     bf16 :   6,291,456 @ 239,075,328   [bh][e][s]
//   ctx    bf16 :   6,291,456 @ 245,366,784   [b*1024+s][768]

typedef __attribute__((ext_vector_type(8))) short bf16x8;
typedef __attribute__((ext_vector_type(4))) float f32x4;
typedef unsigned short u16;

__device__ __forceinline__ u16 f2bf(float f) {
  unsigned u = __float_as_uint(f);
  return (u16)((u + 0x7fffu + ((u >> 16) & 1u)) >> 16);
}
__device__ __forceinline__ float bf2f(u16 h) {
  return __uint_as_float(((unsigned)h) << 16);
}

__device__ __forceinline__ void async16(const void* g, void* l) {
  __builtin_amdgcn_global_load_lds(
      (const __attribute__((address_space(1))) unsigned int*)g,
      (__attribute__((address_space(3))) unsigned int*)l, 16, 0, 0);
}

#define MFMA(a, b, c) __builtin_amdgcn_mfma_f32_16x16x32_bf16((a), (b), (c), 0, 0, 0)

// ---------------- K1: qkv(hi,lo) = x @ Wqkv^T, split-bf16 (3-MFMA) ----------------
// M=4096 N=2304 K=768; fp32 inputs split to hi/lo during LDS staging.
__global__ __launch_bounds__(256) void k_qkv_split(const float* __restrict__ A,
                                                   const float* __restrict__ Bm,
                                                   u16* __restrict__ Chi,
                                                   u16* __restrict__ Clo) {
  __shared__ u16 Ah[128 * 32], Al[128 * 32], Bh[128 * 32], Bl[128 * 32];
  const int t = threadIdx.x, lane = t & 63, wave = t >> 6;
  const int wm = wave >> 1, wn = wave & 1;
  const int quad = lane >> 4, l16 = lane & 15;
  const int m0 = blockIdx.y * 128, n0 = blockIdx.x * 128;
  f32x4 acc[4][4];
#pragma unroll
  for (int i = 0; i < 4; ++i)
#pragma unroll
    for (int j = 0; j < 4; ++j) acc[i][j] = (f32x4){0.f, 0.f, 0.f, 0.f};
  for (int k0 = 0; k0 < 768; k0 += 32) {
    __syncthreads();
#pragma unroll
    for (int p = 0; p < 4; ++p) {
      const int r = p * 32 + (t >> 3), c = (t & 7) * 4;
      float4 av = *(const float4*)&A[(size_t)(m0 + r) * 768 + k0 + c];
      float4 bv = *(const float4*)&Bm[(size_t)(n0 + r) * 768 + k0 + c];
      ushort4 ah = make_ushort4(f2bf(av.x), f2bf(av.y), f2bf(av.z), f2bf(av.w));
      ushort4 al = make_ushort4(f2bf(av.x - bf2f(ah.x)), f2bf(av.y - bf2f(ah.y)),
                                f2bf(av.z - bf2f(ah.z)), f2bf(av.w - bf2f(ah.w)));
      ushort4 bh = make_ushort4(f2bf(bv.x), f2bf(bv.y), f2bf(bv.z), f2bf(bv.w));
      ushort4 bl = make_ushort4(f2bf(bv.x - bf2f(bh.x)), f2bf(bv.y - bf2f(bh.y)),
                                f2bf(bv.z - bf2f(bh.z)), f2bf(bv.w - bf2f(bh.w)));
      *(ushort4*)&Ah[r * 32 + c] = ah;
      *(ushort4*)&Al[r * 32 + c] = al;
      *(ushort4*)&Bh[r * 32 + c] = bh;
      *(ushort4*)&Bl[r * 32 + c] = bl;
    }
    __syncthreads();
    bf16x8 afh[4], afl[4], bfh[4], bfl[4];
#pragma unroll
    for (int i = 0; i < 4; ++i) {
      const int ro = (wm * 64 + i * 16 + l16) * 32 + quad * 8;
      afh[i] = *(const bf16x8*)&Ah[ro];
      afl[i] = *(const bf16x8*)&Al[ro];
    }
#pragma unroll
    for (int j = 0; j < 4; ++j) {
      const int ro = (wn * 64 + j * 16 + l16) * 32 + quad * 8;
      bfh[j] = *(const bf16x8*)&Bh[ro];
      bfl[j] = *(const bf16x8*)&Bl[ro];
    }
#pragma unroll
    for (int i = 0; i < 4; ++i)
#pragma unroll
      for (int j = 0; j < 4; ++j) {
        acc[i][j] = MFMA(afh[i], bfh[j], acc[i][j]);
        acc[i][j] = MFMA(afh[i], bfl[j], acc[i][j]);
        acc[i][j] = MFMA(afl[i], bfh[j], acc[i][j]);
      }
  }
#pragma unroll
  for (int i = 0; i < 4; ++i)
#pragma unroll
    for (int j = 0; j < 4; ++j)
#pragma unroll
      for (int r = 0; r < 4; ++r) {
        const int row = m0 + wm * 64 + i * 16 + quad * 4 + r;
        const int col = n0 + wn * 64 + j * 16 + l16;
        const float v = acc[i][j][r];
        const u16 hi = f2bf(v);
        Chi[(size_t)row * 2304 + col] = hi;
        Clo[(size_t)row * 2304 + col] = f2bf(v - bf2f(hi));
      }
}

// ---------------- K1b: vT[bh][e][s] = qkv_hi[b,s,1536+h*64+e] ----------------
__global__ __launch_bounds__(256) void k_vt(const u16* __restrict__ qkvb,
                                            u16* __restrict__ vT) {
  __shared__ u16 tile[64][68];
  const int t = threadIdx.x;
  const int s0 = blockIdx.x * 64, bh = blockIdx.y;
  const int b = bh / 12, h = bh % 12;
  const u16* src = qkvb + ((size_t)(b * 1024 + s0)) * 2304 + 1536 + h * 64;
#pragma unroll
  for (int p = 0; p < 4; ++p) {
    int r = p * 16 + (t >> 4), c = (t & 15) * 4;
    *(ushort4*)&tile[r][c] = *(const ushort4*)&src[(size_t)r * 2304 + c];
  }
  __syncthreads();
  u16* dst = vT + ((size_t)bh * 64) * 1024 + s0;
#pragma unroll
  for (int p = 0; p < 4; ++p) {
    int e = p * 16 + (t >> 4), sc = (t & 15) * 4;
    ushort4 o = make_ushort4(tile[sc + 0][e], tile[sc + 1][e], tile[sc + 2][e], tile[sc + 3][e]);
    *(ushort4*)&dst[(size_t)e * 1024 + sc] = o;
  }
}

// ---------------- K2: scores(fp32) = Q @ K^T per (b,h), split-bf16 ----------------
__global__ __launch_bounds__(256) void k_qk_split(const u16* __restrict__ qhi,
                                                  const u16* __restrict__ qlo,
                                                  float* __restrict__ scores) {
  __shared__ u16 Ah[128 * 32], Al[128 * 32], Bh[128 * 32], Bl[128 * 32];
  const int t = threadIdx.x, lane = t & 63, wave = t >> 6;
  const int wm = wave >> 1, wn = wave & 1;
  const int quad = lane >> 4, l16 = lane & 15;
  const int bh = blockIdx.z, b = bh / 12, h = bh % 12;
  const int m0 = blockIdx.y * 128, n0 = blockIdx.x * 128;
  const int srow = t >> 2, sch = (t & 3) * 8;
  const size_t qoff = (size_t)b * 1024 * 2304 + h * 64;
  float* C = scores + ((size_t)bh << 20);
  f32x4 acc[4][4];
#pragma unroll
  for (int i = 0; i < 4; ++i)
#pragma unroll
    for (int j = 0; j < 4; ++j) acc[i][j] = (f32x4){0.f, 0.f, 0.f, 0.f};
  for (int k0 = 0; k0 < 64; k0 += 32) {
    const size_t ga = qoff + (size_t)(m0 + srow) * 2304 + k0 + sch;
    const size_t gb = qoff + 768 + (size_t)(n0 + srow) * 2304 + k0 + sch;
    __syncthreads();
    async16(qhi + ga, &Ah[t * 8]);
    async16(qhi + ga + (size_t)64 * 2304, &Ah[2048 + t * 8]);
    async16(qlo + ga, &Al[t * 8]);
    async16(qlo + ga + (size_t)64 * 2304, &Al[2048 + t * 8]);
    async16(qhi + gb, &Bh[t * 8]);
    async16(qhi + gb + (size_t)64 * 2304, &Bh[2048 + t * 8]);
    async16(qlo + gb, &Bl[t * 8]);
    async16(qlo + gb + (size_t)64 * 2304, &Bl[2048 + t * 8]);
    __syncthreads();
    bf16x8 afh[4], afl[4], bfh[4], bfl[4];
#pragma unroll
    for (int i = 0; i < 4; ++i) {
      const int ro = (wm * 64 + i * 16 + l16) * 32 + quad * 8;
      afh[i] = *(const bf16x8*)&Ah[ro];
      afl[i] = *(const bf16x8*)&Al[ro];
    }
#pragma unroll
    for (int j = 0; j < 4; ++j) {
      const int ro = (wn * 64 + j * 16 + l16) * 32 + quad * 8;
      bfh[j] = *(const bf16x8*)&Bh[ro];
      bfl[j] = *(const bf16x8*)&Bl[ro];
    }
#pragma unroll
    for (int i = 0; i < 4; ++i)
#pragma unroll
      for (int j = 0; j < 4; ++j) {
        acc[i][j] = MFMA(afh[i], bfh[j], acc[i][j]);
        acc[i][j] = MFMA(afh[i], bfl[j], acc[i][j]);
        acc[i][j] = MFMA(afl[i], bfh[j], acc[i][j]);
      }
  }
#pragma unroll
  for (int i = 0; i < 4; ++i)
#pragma unroll
    for (int j = 0; j < 4; ++j)
#pragma unroll
      for (int r = 0; r < 4; ++r) {
        const int row = m0 + wm * 64 + i * 16 + quad * 4 + r;
        const int col = n0 + wn * 64 + j * 16 + l16;
        C[(size_t)row * 1024 + col] = acc[i][j][r];
      }
}

// ---------------- K3: mix1 -> softmax -> mix2, fp32 in place ----------------
__global__ __launch_bounds__(256) void k_mix(float* __restrict__ sc,
                                             const float* __restrict__ Wl,
                                             const float* __restrict__ bl,
                                             const float* __restrict__ Ww,
                                             const float* __restrict__ bw) {
  __shared__ float wl_s[144], ww_s[144], bl_s[12], bw_s[12];
  __shared__ float red[4][12];
  const int t = threadIdx.x, lane = t & 63, wave = t >> 6;
  const int bq = blockIdx.x, b = bq >> 10, q = bq & 1023;
  if (t < 144) { wl_s[t] = Wl[t]; ww_s[t] = Ww[t]; }
  if (t < 12)  { bl_s[t] = bl[t]; bw_s[t] = bw[t]; }
  float raw[12][4];
#pragma unroll
  for (int h = 0; h < 12; ++h) {
    const float* p = sc + (((size_t)(b * 12 + h) * 1024 + q) << 10);
    float2 a = *(const float2*)&p[2 * t];
    float2 c = *(const float2*)&p[512 + 2 * t];
    raw[h][0] = a.x; raw[h][1] = a.y; raw[h][2] = c.x; raw[h][3] = c.y;
  }
  __syncthreads();
  float lg[12][4];
#pragma unroll
  for (int g = 0; g < 12; ++g) {
    float w[12];
#pragma unroll
    for (int h = 0; h < 12; ++h) w[h] = wl_s[g * 12 + h];
#pragma unroll
    for (int kk = 0; kk < 4; ++kk) {
      float v = bl_s[g];
#pragma unroll
      for (int h = 0; h < 12; ++h) v = fmaf(w[h], raw[h][kk], v);
      lg[g][kk] = v;
    }
  }
  float mx[12];
#pragma unroll
  for (int g = 0; g < 12; ++g)
    mx[g] = fmaxf(fmaxf(lg[g][0], lg[g][1]), fmaxf(lg[g][2], lg[g][3]));
#pragma unroll
  for (int off = 32; off > 0; off >>= 1)
#pragma unroll
    for (int g = 0; g < 12; ++g) mx[g] = fmaxf(mx[g], __shfl_xor(mx[g], off));
  if (lane == 0) {
#pragma unroll
    for (int g = 0; g < 12; ++g) red[wave][g] = mx[g];
  }
  __syncthreads();
#pragma unroll
  for (int g = 0; g < 12; ++g)
    mx[g] = fmaxf(fmaxf(red[0][g], red[1][g]), fmaxf(red[2][g], red[3][g]));
  float sm[12];
#pragma unroll
  for (int g = 0; g < 12; ++g) {
    float s = 0.f;
#pragma unroll
    for (int kk = 0; kk < 4; ++kk) {
      float e = __expf(lg[g][kk] - mx[g]);
      lg[g][kk] = e;
      s += e;
    }
    sm[g] = s;
  }
#pragma unroll
  for (int off = 32; off > 0; off >>= 1)
#pragma unroll
    for (int g = 0; g < 12; ++g) sm[g] += __shfl_xor(sm[g], off);
  __syncthreads();
  if (lane == 0) {
#pragma unroll
    for (int g = 0; g < 12; ++g) red[wave][g] = sm[g];
  }
  __syncthreads();
#pragma unroll
  for (int g = 0; g < 12; ++g) {
    float inv = 1.0f / (red[0][g] + red[1][g] + red[2][g] + red[3][g]);
#pragma unroll
    for (int kk = 0; kk < 4; ++kk) lg[g][kk] *= inv;
  }
#pragma unroll
  for (int g2 = 0; g2 < 12; ++g2) {
    float w[12];
#pragma unroll
    for (int h = 0; h < 12; ++h) w[h] = ww_s[g2 * 12 + h];
    float o[4];
#pragma unroll
    for (int kk = 0; kk < 4; ++kk) {
      float v = bw_s[g2];
#pragma unroll
      for (int h = 0; h < 12; ++h) v = fmaf(w[h], lg[h][kk], v);
      o[kk] = v;
    }
    float* p = sc + (((size_t)(b * 12 + g2) * 1024 + q) << 10);
    *(float2*)&p[2 * t] = make_float2(o[0], o[1]);
    *(float2*)&p[512 + 2 * t] = make_float2(o[2], o[3]);
  }
}

// ---------------- K4: ctx = P(fp32) @ V per (b,h), plain bf16 ----------------
__global__ __launch_bounds__(256) void k_pv(const float* __restrict__ scores,
                                            const u16* __restrict__ vT,
                                            u16* __restrict__ ctx) {
  __shared__ u16 As[128 * 32];
  __shared__ u16 Bs[64 * 32];
  const int t = threadIdx.x, lane = t & 63, wave = t >> 6;
  const int wm = wave >> 1, wn = wave & 1;
  const int quad = lane >> 4, l16 = lane & 15;
  const int bh = blockIdx.y, b = bh / 12, h = bh % 12;
  const int m0 = blockIdx.x * 128;
  const float* P = scores + ((size_t)bh << 20);
  const u16* V = vT + (size_t)bh * 64 * 1024;
  f32x4 acc[4][2];
#pragma unroll
  for (int i = 0; i < 4; ++i)
#pragma unroll
    for (int j = 0; j < 2; ++j) acc[i][j] = (f32x4){0.f, 0.f, 0.f, 0.f};
  for (int k0 = 0; k0 < 1024; k0 += 32) {
    __syncthreads();
    async16(V + (size_t)(t >> 2) * 1024 + k0 + (t & 3) * 8, &Bs[t * 8]);
#pragma unroll
    for (int p = 0; p < 4; ++p) {
      int r = p * 32 + (t >> 3), c = (t & 7) * 4;
      float4 v = *(const float4*)&P[(size_t)(m0 + r) * 1024 + k0 + c];
      *(ushort4*)&As[r * 32 + c] = make_ushort4(f2bf(v.x), f2bf(v.y), f2bf(v.z), f2bf(v.w));
    }
    __syncthreads();
    bf16x8 af[4], bfr[2];
#pragma unroll
    for (int i = 0; i < 4; ++i) af[i] = *(const bf16x8*)&As[(wm * 64 + i * 16 + l16) * 32 + quad * 8];
#pragma unroll
    for (int j = 0; j < 2; ++j) bfr[j] = *(const bf16x8*)&Bs[(wn * 32 + j * 16 + l16) * 32 + quad * 8];
#pragma unroll
    for (int i = 0; i < 4; ++i)
#pragma unroll
      for (int j = 0; j < 2; ++j) acc[i][j] = MFMA(af[i], bfr[j], acc[i][j]);
  }
#pragma unroll
  for (int i = 0; i < 4; ++i)
#pragma unroll
    for (int j = 0; j < 2; ++j)
#pragma unroll
      for (int r = 0; r < 4; ++r) {
        int q = m0 + wm * 64 + i * 16 + quad * 4 + r;
        int e = wn * 32 + j * 16 + l16;
        ctx[(size_t)(b * 1024 + q) * 768 + h * 64 + e] = f2bf(acc[i][j][r]);
      }
}

// ---------------- K5: out = ctx @ Wp^T + bp (Wp cast in-kernel) ----------------
__global__ __launch_bounds__(256) void k_oproj(const u16* __restrict__ A,
                                               const float* __restrict__ Wp,
                                               const float* __restrict__ bp,
                                               float* __restrict__ out) {
  __shared__ u16 As[128 * 32];
  __shared__ u16 Bs[128 * 32];
  const int t = threadIdx.x, lane = t & 63, wave = t >> 6;
  const int wm = wave >> 1, wn = wave & 1;
  const int quad = lane >> 4, l16 = lane & 15;
  const int m0 = blockIdx.y * 128, n0 = blockIdx.x * 128;
  const int srow = t >> 2, sch = (t & 3) * 8;
  f32x4 acc[4][4];
#pragma unroll
  for (int i = 0; i < 4; ++i)
#pragma unroll
    for (int j = 0; j < 4; ++j) acc[i][j] = (f32x4){0.f, 0.f, 0.f, 0.f};
  for (int k0 = 0; k0 < 768; k0 += 32) {
    __syncthreads();
    const u16* ga = A + (size_t)(m0 + srow) * 768 + k0 + sch;
    async16(ga, &As[t * 8]);
    async16(ga + (size_t)64 * 768, &As[2048 + t * 8]);
#pragma unroll
    for (int p = 0; p < 4; ++p) {
      int r = p * 32 + (t >> 3), c = (t & 7) * 4;
      float4 wv = *(const float4*)&Wp[(size_t)(n0 + r) * 768 + k0 + c];
      *(ushort4*)&Bs[r * 32 + c] = make_ushort4(f2bf(wv.x), f2bf(wv.y), f2bf(wv.z), f2bf(wv.w));
    }
    __syncthreads();
    bf16x8 af[4], bfr[4];
#pragma unroll
    for (int i = 0; i < 4; ++i) af[i] = *(const bf16x8*)&As[(wm * 64 + i * 16 + l16) * 32 + quad * 8];
#pragma unroll
    for (int j = 0; j < 4; ++j) bfr[j] = *(const bf16x8*)&Bs[(wn * 64 + j * 16 + l16) * 32 + quad * 8];
#pragma unroll
    for (int i = 0; i < 4; ++i)
#pragma unroll
      for (int j = 0; j < 4; ++j) acc[i][j] = MFMA(af[i], bfr[j], acc[i][j]);
  }
#pragma unroll
  for (int i = 0; i < 4; ++i)
#pragma unroll
    for (int j = 0; j < 4; ++j)
#pragma unroll
      for (int r = 0; r < 4; ++r) {
        const int row = m0 + wm * 64 + i * 16 + quad * 4 + r;
        const int col = n0 + wn * 64 + j * 16 + l16;
        out[(size_t)row * 768 + col] = acc[i][j][r] + bp[col];
      }
}

extern "C" void kernel_launch(void* const* d_in, const int* in_sizes, int n_in,
                              void* d_out, int out_size, void* d_ws, size_t ws_size,
                              hipStream_t stream) {
  const float* x    = (const float*)d_in[0];
  const float* Wqkv = (const float*)d_in[1];
  const float* Wl   = (const float*)d_in[2];
  const float* bl   = (const float*)d_in[3];
  const float* Ww   = (const float*)d_in[4];
  const float* bw   = (const float*)d_in[5];
  const float* Wp   = (const float*)d_in[6];
  const float* bp   = (const float*)d_in[7];
  float* out = (float*)d_out;

  char* ws = (char*)d_ws;
  float* scores = (float*)(ws + 0);             // 201,326,592 B
  u16* qkv_hi   = (u16*)(ws + 201326592ull);    //  18,874,368 B
  u16* qkv_lo   = (u16*)(ws + 220200960ull);    //  18,874,368 B
  u16* vT       = (u16*)(ws + 239075328ull);    //   6,291,456 B
  u16* ctx      = (u16*)(ws + 245366784ull);    //   6,291,456 B

  hipLaunchKernelGGL(k_qkv_split, dim3(18, 32),   dim3(256), 0, stream, x, Wqkv, qkv_hi, qkv_lo);
  hipLaunchKernelGGL(k_vt,        dim3(16, 48),   dim3(256), 0, stream, qkv_hi, vT);
  hipLaunchKernelGGL(k_qk_split,  dim3(8, 8, 48), dim3(256), 0, stream, qkv_hi, qkv_lo, scores);
  hipLaunchKernelGGL(k_mix,       dim3(4096),     dim3(256), 0, stream, scores, Wl, bl, Ww, bw);
  hipLaunchKernelGGL(k_pv,        dim3(8, 48),    dim3(256), 0, stream, scores, vT, ctx);
  hipLaunchKernelGGL(k_oproj,     dim3(6, 32),    dim3(256), 0, stream, ctx, Wp, bp, out);
}

// Round 4
// 310.686 us; speedup vs baseline: 2.3403x; 1.2429x over previous
//
#include <hip/hip_runtime.h>
#include <hip/hip_fp16.h>
#include <math.h>

// B=4, S=1024, D=768, H=12, E=64, 3D=2304
// Workspace layout (bytes), total 171,835,392 (< 240 MiB):
//   sc16   fp16->bf16 in place : 100,663,296 @ 0           [bh][q][k]
//   qkv_hi bf16 :  18,874,368 @ 100,663,296
//   qkv_lo bf16 :  18,874,368 @ 119,537,664
//   vT     bf16 :   6,291,456 @ 138,412,032   [bh][e][s]
//   ctx    bf16 :   6,291,456 @ 144,703,488   [b*1024+s][768]
//   x_hi   bf16 :   6,291,456 @ 150,994,944
//   x_lo   bf16 :   6,291,456 @ 157,286,400
//   wq_hi  bf16 :   3,538,944 @ 163,577,856
//   wq_lo  bf16 :   3,538,944 @ 167,116,800
//   wp_b   bf16 :   1,179,648 @ 170,655,744

typedef __attribute__((ext_vector_type(8))) short bf16x8;
typedef __attribute__((ext_vector_type(4))) float f32x4;
typedef unsigned short u16;

__device__ __forceinline__ u16 f2bf(float f) {
  unsigned u = __float_as_uint(f);
  return (u16)((u + 0x7fffu + ((u >> 16) & 1u)) >> 16);
}
__device__ __forceinline__ float bf2f(u16 h) {
  return __uint_as_float(((unsigned)h) << 16);
}

__device__ __forceinline__ void async16(const void* g, void* l) {
  __builtin_amdgcn_global_load_lds(
      (const __attribute__((address_space(1))) unsigned int*)g,
      (__attribute__((address_space(3))) unsigned int*)l, 16, 0, 0);
}

#define MFMA(a, b, c) __builtin_amdgcn_mfma_f32_16x16x32_bf16((a), (b), (c), 0, 0, 0)

// ---------------- split fp32 -> (hi, lo) bf16, vectorized x4 ----------------
__global__ __launch_bounds__(256) void k_split(const float* __restrict__ s,
                                               u16* __restrict__ hi,
                                               u16* __restrict__ lo, int n4) {
  int i = blockIdx.x * 256 + threadIdx.x;
  if (i < n4) {
    float4 v = ((const float4*)s)[i];
    ushort4 h = make_ushort4(f2bf(v.x), f2bf(v.y), f2bf(v.z), f2bf(v.w));
    ushort4 l = make_ushort4(f2bf(v.x - bf2f(h.x)), f2bf(v.y - bf2f(h.y)),
                             f2bf(v.z - bf2f(h.z)), f2bf(v.w - bf2f(h.w)));
    ((ushort4*)hi)[i] = h;
    ((ushort4*)lo)[i] = l;
  }
}

// ---------------- cast fp32 -> bf16, vectorized x4 ----------------
__global__ __launch_bounds__(256) void k_cast(const float* __restrict__ s,
                                              u16* __restrict__ d, int n4) {
  int i = blockIdx.x * 256 + threadIdx.x;
  if (i < n4) {
    float4 v = ((const float4*)s)[i];
    ((ushort4*)d)[i] = make_ushort4(f2bf(v.x), f2bf(v.y), f2bf(v.z), f2bf(v.w));
  }
}

// ---------------- K1: qkv(hi,lo) = x @ Wqkv^T, split-bf16 (3-MFMA), async16 staged ----------------
// M=4096 N=2304 K=768
__global__ __launch_bounds__(256) void k_qkv_mm3(const u16* __restrict__ Axh,
                                                 const u16* __restrict__ Axl,
                                                 const u16* __restrict__ Bwh,
                                                 const u16* __restrict__ Bwl,
                                                 u16* __restrict__ Chi,
                                                 u16* __restrict__ Clo) {
  __shared__ u16 Ah[128 * 32], Al[128 * 32], Bh[128 * 32], Bl[128 * 32];
  const int t = threadIdx.x, lane = t & 63, wave = t >> 6;
  const int wm = wave >> 1, wn = wave & 1;
  const int quad = lane >> 4, l16 = lane & 15;
  const int m0 = blockIdx.y * 128, n0 = blockIdx.x * 128;
  const int srow = t >> 2, sch = (t & 3) * 8;
  f32x4 acc[4][4];
#pragma unroll
  for (int i = 0; i < 4; ++i)
#pragma unroll
    for (int j = 0; j < 4; ++j) acc[i][j] = (f32x4){0.f, 0.f, 0.f, 0.f};
  for (int k0 = 0; k0 < 768; k0 += 32) {
    const size_t ga = (size_t)(m0 + srow) * 768 + k0 + sch;
    const size_t gb = (size_t)(n0 + srow) * 768 + k0 + sch;
    __syncthreads();
    async16(Axh + ga, &Ah[t * 8]);
    async16(Axh + ga + (size_t)64 * 768, &Ah[2048 + t * 8]);
    async16(Axl + ga, &Al[t * 8]);
    async16(Axl + ga + (size_t)64 * 768, &Al[2048 + t * 8]);
    async16(Bwh + gb, &Bh[t * 8]);
    async16(Bwh + gb + (size_t)64 * 768, &Bh[2048 + t * 8]);
    async16(Bwl + gb, &Bl[t * 8]);
    async16(Bwl + gb + (size_t)64 * 768, &Bl[2048 + t * 8]);
    __syncthreads();
    bf16x8 afh[4], afl[4], bfh[4], bfl[4];
#pragma unroll
    for (int i = 0; i < 4; ++i) {
      const int ro = (wm * 64 + i * 16 + l16) * 32 + quad * 8;
      afh[i] = *(const bf16x8*)&Ah[ro];
      afl[i] = *(const bf16x8*)&Al[ro];
    }
#pragma unroll
    for (int j = 0; j < 4; ++j) {
      const int ro = (wn * 64 + j * 16 + l16) * 32 + quad * 8;
      bfh[j] = *(const bf16x8*)&Bh[ro];
      bfl[j] = *(const bf16x8*)&Bl[ro];
    }
#pragma unroll
    for (int i = 0; i < 4; ++i)
#pragma unroll
      for (int j = 0; j < 4; ++j) {
        acc[i][j] = MFMA(afh[i], bfh[j], acc[i][j]);
        acc[i][j] = MFMA(afh[i], bfl[j], acc[i][j]);
        acc[i][j] = MFMA(afl[i], bfh[j], acc[i][j]);
      }
  }
#pragma unroll
  for (int i = 0; i < 4; ++i)
#pragma unroll
    for (int j = 0; j < 4; ++j)
#pragma unroll
      for (int r = 0; r < 4; ++r) {
        const int row = m0 + wm * 64 + i * 16 + quad * 4 + r;
        const int col = n0 + wn * 64 + j * 16 + l16;
        const float v = acc[i][j][r];
        const u16 hi = f2bf(v);
        Chi[(size_t)row * 2304 + col] = hi;
        Clo[(size_t)row * 2304 + col] = f2bf(v - bf2f(hi));
      }
}

// ---------------- K1b: vT[bh][e][s] = qkv_hi[b,s,1536+h*64+e] ----------------
__global__ __launch_bounds__(256) void k_vt(const u16* __restrict__ qkvb,
                                            u16* __restrict__ vT) {
  __shared__ u16 tile[64][68];
  const int t = threadIdx.x;
  const int s0 = blockIdx.x * 64, bh = blockIdx.y;
  const int b = bh / 12, h = bh % 12;
  const u16* src = qkvb + ((size_t)(b * 1024 + s0)) * 2304 + 1536 + h * 64;
#pragma unroll
  for (int p = 0; p < 4; ++p) {
    int r = p * 16 + (t >> 4), c = (t & 15) * 4;
    *(ushort4*)&tile[r][c] = *(const ushort4*)&src[(size_t)r * 2304 + c];
  }
  __syncthreads();
  u16* dst = vT + ((size_t)bh * 64) * 1024 + s0;
#pragma unroll
  for (int p = 0; p < 4; ++p) {
    int e = p * 16 + (t >> 4), sc = (t & 15) * 4;
    ushort4 o = make_ushort4(tile[sc + 0][e], tile[sc + 1][e], tile[sc + 2][e], tile[sc + 3][e]);
    *(ushort4*)&dst[(size_t)e * 1024 + sc] = o;
  }
}

// ---------------- K2: scores(fp16) = Q @ K^T per (b,h), split-bf16 ----------------
__global__ __launch_bounds__(256) void k_qk_split(const u16* __restrict__ qhi,
                                                  const u16* __restrict__ qlo,
                                                  __half* __restrict__ scores) {
  __shared__ u16 Ah[128 * 32], Al[128 * 32], Bh[128 * 32], Bl[128 * 32];
  const int t = threadIdx.x, lane = t & 63, wave = t >> 6;
  const int wm = wave >> 1, wn = wave & 1;
  const int quad = lane >> 4, l16 = lane & 15;
  const int bh = blockIdx.z, b = bh / 12, h = bh % 12;
  const int m0 = blockIdx.y * 128, n0 = blockIdx.x * 128;
  const int srow = t >> 2, sch = (t & 3) * 8;
  const size_t qoff = (size_t)b * 1024 * 2304 + h * 64;
  __half* C = scores + ((size_t)bh << 20);
  f32x4 acc[4][4];
#pragma unroll
  for (int i = 0; i < 4; ++i)
#pragma unroll
    for (int j = 0; j < 4; ++j) acc[i][j] = (f32x4){0.f, 0.f, 0.f, 0.f};
  for (int k0 = 0; k0 < 64; k0 += 32) {
    const size_t ga = qoff + (size_t)(m0 + srow) * 2304 + k0 + sch;
    const size_t gb = qoff + 768 + (size_t)(n0 + srow) * 2304 + k0 + sch;
    __syncthreads();
    async16(qhi + ga, &Ah[t * 8]);
    async16(qhi + ga + (size_t)64 * 2304, &Ah[2048 + t * 8]);
    async16(qlo + ga, &Al[t * 8]);
    async16(qlo + ga + (size_t)64 * 2304, &Al[2048 + t * 8]);
    async16(qhi + gb, &Bh[t * 8]);
    async16(qhi + gb + (size_t)64 * 2304, &Bh[2048 + t * 8]);
    async16(qlo + gb, &Bl[t * 8]);
    async16(qlo + gb + (size_t)64 * 2304, &Bl[2048 + t * 8]);
    __syncthreads();
    bf16x8 afh[4], afl[4], bfh[4], bfl[4];
#pragma unroll
    for (int i = 0; i < 4; ++i) {
      const int ro = (wm * 64 + i * 16 + l16) * 32 + quad * 8;
      afh[i] = *(const bf16x8*)&Ah[ro];
      afl[i] = *(const bf16x8*)&Al[ro];
    }
#pragma unroll
    for (int j = 0; j < 4; ++j) {
      const int ro = (wn * 64 + j * 16 + l16) * 32 + quad * 8;
      bfh[j] = *(const bf16x8*)&Bh[ro];
      bfl[j] = *(const bf16x8*)&Bl[ro];
    }
#pragma unroll
    for (int i = 0; i < 4; ++i)
#pragma unroll
      for (int j = 0; j < 4; ++j) {
        acc[i][j] = MFMA(afh[i], bfh[j], acc[i][j]);
        acc[i][j] = MFMA(afh[i], bfl[j], acc[i][j]);
        acc[i][j] = MFMA(afl[i], bfh[j], acc[i][j]);
      }
  }
#pragma unroll
  for (int i = 0; i < 4; ++i)
#pragma unroll
    for (int j = 0; j < 4; ++j)
#pragma unroll
      for (int r = 0; r < 4; ++r) {
        const int row = m0 + wm * 64 + i * 16 + quad * 4 + r;
        const int col = n0 + wn * 64 + j * 16 + l16;
        C[(size_t)row * 1024 + col] = __float2half(acc[i][j][r]);
      }
}

// ---------------- K3: mix1 -> softmax -> mix2; fp16 in, bf16 out, in place ----------------
__global__ __launch_bounds__(256) void k_mix(u16* __restrict__ scbuf,
                                             const float* __restrict__ Wl,
                                             const float* __restrict__ bl,
                                             const float* __restrict__ Ww,
                                             const float* __restrict__ bw) {
  __shared__ float wl_s[144], ww_s[144], bl_s[12], bw_s[12];
  __shared__ float red[4][12];
  const int t = threadIdx.x, lane = t & 63, wave = t >> 6;
  const int bq = blockIdx.x, b = bq >> 10, q = bq & 1023;
  if (t < 144) { wl_s[t] = Wl[t]; ww_s[t] = Ww[t]; }
  if (t < 12)  { bl_s[t] = bl[t]; bw_s[t] = bw[t]; }
  float raw[12][4];
#pragma unroll
  for (int h = 0; h < 12; ++h) {
    const __half* p = (const __half*)scbuf + (((size_t)(b * 12 + h) * 1024 + q) << 10);
    __half2 a = *(const __half2*)&p[2 * t];
    __half2 c = *(const __half2*)&p[512 + 2 * t];
    raw[h][0] = __half2float(a.x); raw[h][1] = __half2float(a.y);
    raw[h][2] = __half2float(c.x); raw[h][3] = __half2float(c.y);
  }
  __syncthreads();
  float lg[12][4];
#pragma unroll
  for (int g = 0; g < 12; ++g) {
    float w[12];
#pragma unroll
    for (int h = 0; h < 12; ++h) w[h] = wl_s[g * 12 + h];
#pragma unroll
    for (int kk = 0; kk < 4; ++kk) {
      float v = bl_s[g];
#pragma unroll
      for (int h = 0; h < 12; ++h) v = fmaf(w[h], raw[h][kk], v);
      lg[g][kk] = v;
    }
  }
  float mx[12];
#pragma unroll
  for (int g = 0; g < 12; ++g)
    mx[g] = fmaxf(fmaxf(lg[g][0], lg[g][1]), fmaxf(lg[g][2], lg[g][3]));
#pragma unroll
  for (int off = 32; off > 0; off >>= 1)
#pragma unroll
    for (int g = 0; g < 12; ++g) mx[g] = fmaxf(mx[g], __shfl_xor(mx[g], off));
  if (lane == 0) {
#pragma unroll
    for (int g = 0; g < 12; ++g) red[wave][g] = mx[g];
  }
  __syncthreads();
#pragma unroll
  for (int g = 0; g < 12; ++g)
    mx[g] = fmaxf(fmaxf(red[0][g], red[1][g]), fmaxf(red[2][g], red[3][g]));
  float sm[12];
#pragma unroll
  for (int g = 0; g < 12; ++g) {
    float s = 0.f;
#pragma unroll
    for (int kk = 0; kk < 4; ++kk) {
      float e = __expf(lg[g][kk] - mx[g]);
      lg[g][kk] = e;
      s += e;
    }
    sm[g] = s;
  }
#pragma unroll
  for (int off = 32; off > 0; off >>= 1)
#pragma unroll
    for (int g = 0; g < 12; ++g) sm[g] += __shfl_xor(sm[g], off);
  __syncthreads();
  if (lane == 0) {
#pragma unroll
    for (int g = 0; g < 12; ++g) red[wave][g] = sm[g];
  }
  __syncthreads();
#pragma unroll
  for (int g = 0; g < 12; ++g) {
    float inv = 1.0f / (red[0][g] + red[1][g] + red[2][g] + red[3][g]);
#pragma unroll
    for (int kk = 0; kk < 4; ++kk) lg[g][kk] *= inv;
  }
#pragma unroll
  for (int g2 = 0; g2 < 12; ++g2) {
    float w[12];
#pragma unroll
    for (int h = 0; h < 12; ++h) w[h] = ww_s[g2 * 12 + h];
    float o[4];
#pragma unroll
    for (int kk = 0; kk < 4; ++kk) {
      float v = bw_s[g2];
#pragma unroll
      for (int h = 0; h < 12; ++h) v = fmaf(w[h], lg[h][kk], v);
      o[kk] = v;
    }
    u16* p = scbuf + (((size_t)(b * 12 + g2) * 1024 + q) << 10);
    *(ushort2*)&p[2 * t] = make_ushort2(f2bf(o[0]), f2bf(o[1]));
    *(ushort2*)&p[512 + 2 * t] = make_ushort2(f2bf(o[2]), f2bf(o[3]));
  }
}

// ---------------- K4: ctx = P(bf16) @ V per (b,h), pure async16 GEMM ----------------
// M=1024 N=64 K=1024; BM=128 BN=64; waves 2x2, each 64x32 (4x2 frags)
__global__ __launch_bounds__(256) void k_pv(const u16* __restrict__ probs,
                                            const u16* __restrict__ vT,
                                            u16* __restrict__ ctx) {
  __shared__ u16 As[128 * 32];
  __shared__ u16 Bs[64 * 32];
  const int t = threadIdx.x, lane = t & 63, wave = t >> 6;
  const int wm = wave >> 1, wn = wave & 1;
  const int quad = lane >> 4, l16 = lane & 15;
  const int bh = blockIdx.y, b = bh / 12, h = bh % 12;
  const int m0 = blockIdx.x * 128;
  const u16* P = probs + ((size_t)bh << 20);
  const u16* V = vT + (size_t)bh * 64 * 1024;
  const int srow = t >> 2, sch = (t & 3) * 8;
  f32x4 acc[4][2];
#pragma unroll
  for (int i = 0; i < 4; ++i)
#pragma unroll
    for (int j = 0; j < 2; ++j) acc[i][j] = (f32x4){0.f, 0.f, 0.f, 0.f};
  for (int k0 = 0; k0 < 1024; k0 += 32) {
    __syncthreads();
    const u16* ga = P + (size_t)(m0 + srow) * 1024 + k0 + sch;
    async16(ga, &As[t * 8]);
    async16(ga + (size_t)64 * 1024, &As[2048 + t * 8]);
    async16(V + (size_t)srow * 1024 + k0 + sch, &Bs[t * 8]);
    __syncthreads();
    bf16x8 af[4], bfr[2];
#pragma unroll
    for (int i = 0; i < 4; ++i) af[i] = *(const bf16x8*)&As[(wm * 64 + i * 16 + l16) * 32 + quad * 8];
#pragma unroll
    for (int j = 0; j < 2; ++j) bfr[j] = *(const bf16x8*)&Bs[(wn * 32 + j * 16 + l16) * 32 + quad * 8];
#pragma unroll
    for (int i = 0; i < 4; ++i)
#pragma unroll
      for (int j = 0; j < 2; ++j) acc[i][j] = MFMA(af[i], bfr[j], acc[i][j]);
  }
#pragma unroll
  for (int i = 0; i < 4; ++i)
#pragma unroll
    for (int j = 0; j < 2; ++j)
#pragma unroll
      for (int r = 0; r < 4; ++r) {
        int q = m0 + wm * 64 + i * 16 + quad * 4 + r;
        int e = wn * 32 + j * 16 + l16;
        ctx[(size_t)(b * 1024 + q) * 768 + h * 64 + e] = f2bf(acc[i][j][r]);
      }
}

// ---------------- K5: out = ctx @ Wp^T + bp, pure async16 GEMM ----------------
// M=4096 N=768 K=768
__global__ __launch_bounds__(256) void k_oproj(const u16* __restrict__ A,
                                               const u16* __restrict__ Bm,
                                               const float* __restrict__ bp,
                                               float* __restrict__ out) {
  __shared__ u16 As[128 * 32];
  __shared__ u16 Bs[128 * 32];
  const int t = threadIdx.x, lane = t & 63, wave = t >> 6;
  const int wm = wave >> 1, wn = wave & 1;
  const int quad = lane >> 4, l16 = lane & 15;
  const int m0 = blockIdx.y * 128, n0 = blockIdx.x * 128;
  const int srow = t >> 2, sch = (t & 3) * 8;
  f32x4 acc[4][4];
#pragma unroll
  for (int i = 0; i < 4; ++i)
#pragma unroll
    for (int j = 0; j < 4; ++j) acc[i][j] = (f32x4){0.f, 0.f, 0.f, 0.f};
  for (int k0 = 0; k0 < 768; k0 += 32) {
    __syncthreads();
    const u16* ga = A + (size_t)(m0 + srow) * 768 + k0 + sch;
    const u16* gb = Bm + (size_t)(n0 + srow) * 768 + k0 + sch;
    async16(ga, &As[t * 8]);
    async16(ga + (size_t)64 * 768, &As[2048 + t * 8]);
    async16(gb, &Bs[t * 8]);
    async16(gb + (size_t)64 * 768, &Bs[2048 + t * 8]);
    __syncthreads();
    bf16x8 af[4], bfr[4];
#pragma unroll
    for (int i = 0; i < 4; ++i) af[i] = *(const bf16x8*)&As[(wm * 64 + i * 16 + l16) * 32 + quad * 8];
#pragma unroll
    for (int j = 0; j < 4; ++j) bfr[j] = *(const bf16x8*)&Bs[(wn * 64 + j * 16 + l16) * 32 + quad * 8];
#pragma unroll
    for (int i = 0; i < 4; ++i)
#pragma unroll
      for (int j = 0; j < 4; ++j) acc[i][j] = MFMA(af[i], bfr[j], acc[i][j]);
  }
#pragma unroll
  for (int i = 0; i < 4; ++i)
#pragma unroll
    for (int j = 0; j < 4; ++j)
#pragma unroll
      for (int r = 0; r < 4; ++r) {
        const int row = m0 + wm * 64 + i * 16 + quad * 4 + r;
        const int col = n0 + wn * 64 + j * 16 + l16;
        out[(size_t)row * 768 + col] = acc[i][j][r] + bp[col];
      }
}

extern "C" void kernel_launch(void* const* d_in, const int* in_sizes, int n_in,
                              void* d_out, int out_size, void* d_ws, size_t ws_size,
                              hipStream_t stream) {
  const float* x    = (const float*)d_in[0];
  const float* Wqkv = (const float*)d_in[1];
  const float* Wl   = (const float*)d_in[2];
  const float* bl   = (const float*)d_in[3];
  const float* Ww   = (const float*)d_in[4];
  const float* bw   = (const float*)d_in[5];
  const float* Wp   = (const float*)d_in[6];
  const float* bp   = (const float*)d_in[7];
  float* out = (float*)d_out;

  char* ws = (char*)d_ws;
  u16* scbuf  = (u16*)(ws + 0);               // 100,663,296 B (fp16 scores -> bf16 probs)
  u16* qkv_hi = (u16*)(ws + 100663296ull);    //  18,874,368 B
  u16* qkv_lo = (u16*)(ws + 119537664ull);    //  18,874,368 B
  u16* vT     = (u16*)(ws + 138412032ull);    //   6,291,456 B
  u16* ctx    = (u16*)(ws + 144703488ull);    //   6,291,456 B
  u16* x_hi   = (u16*)(ws + 150994944ull);    //   6,291,456 B
  u16* x_lo   = (u16*)(ws + 157286400ull);    //   6,291,456 B
  u16* wq_hi  = (u16*)(ws + 163577856ull);    //   3,538,944 B
  u16* wq_lo  = (u16*)(ws + 167116800ull);    //   3,538,944 B
  u16* wp_b   = (u16*)(ws + 170655744ull);    //   1,179,648 B

  hipLaunchKernelGGL(k_split, dim3(3072), dim3(256), 0, stream, x, x_hi, x_lo, 786432);
  hipLaunchKernelGGL(k_split, dim3(1728), dim3(256), 0, stream, Wqkv, wq_hi, wq_lo, 442368);
  hipLaunchKernelGGL(k_cast,  dim3(576),  dim3(256), 0, stream, Wp, wp_b, 147456);

  hipLaunchKernelGGL(k_qkv_mm3, dim3(18, 32),   dim3(256), 0, stream,
                     x_hi, x_lo, wq_hi, wq_lo, qkv_hi, qkv_lo);
  hipLaunchKernelGGL(k_vt,      dim3(16, 48),   dim3(256), 0, stream, qkv_hi, vT);
  hipLaunchKernelGGL(k_qk_split, dim3(8, 8, 48), dim3(256), 0, stream,
                     qkv_hi, qkv_lo, (__half*)scbuf);
  hipLaunchKernelGGL(k_mix,     dim3(4096),     dim3(256), 0, stream, scbuf, Wl, bl, Ww, bw);
  hipLaunchKernelGGL(k_pv,      dim3(8, 48),    dim3(256), 0, stream, scbuf, vT, ctx);
  hipLaunchKernelGGL(k_oproj,   dim3(6, 32),    dim3(256), 0, stream, ctx, wp_b, bp, out);
}

// Round 5
// 290.277 us; speedup vs baseline: 2.5048x; 1.0703x over previous
//
#include <hip/hip_runtime.h>
#include <hip/hip_fp16.h>
#include <math.h>

// B=4, S=1024, D=768, H=12, E=64, 3D=2304
// Workspace layout (bytes), total 171,835,392 (< 240 MiB):
//   scbuf  fp16 scores -> bf16 probs in place : 100,663,296 @ 0   [bh][q][k]
//   qkv_hi bf16 :  18,874,368 @ 100,663,296
//   qkv_lo bf16 :  18,874,368 @ 119,537,664   (V cols 1536+ unused/garbage)
//   vT     bf16 :   6,291,456 @ 138,412,032   [bh][e][s]
//   ctx    bf16 :   6,291,456 @ 144,703,488   [b*1024+s][768]
//   x_hi   bf16 :   6,291,456 @ 150,994,944
//   x_lo   bf16 :   6,291,456 @ 157,286,400
//   wq_hi  bf16 :   3,538,944 @ 163,577,856
//   wq_lo  bf16 :   3,538,944 @ 167,116,800
//   wp_b   bf16 :   1,179,648 @ 170,655,744

typedef __attribute__((ext_vector_type(8))) short bf16x8;
typedef __attribute__((ext_vector_type(4))) float f32x4;
typedef __attribute__((ext_vector_type(2))) float f32x2;
typedef unsigned short u16;

__device__ __forceinline__ u16 f2bf(float f) {
  unsigned u = __float_as_uint(f);
  return (u16)((u + 0x7fffu + ((u >> 16) & 1u)) >> 16);
}
__device__ __forceinline__ float bf2f(u16 h) {
  return __uint_as_float(((unsigned)h) << 16);
}

__device__ __forceinline__ void async16(const void* g, void* l) {
  __builtin_amdgcn_global_load_lds(
      (const __attribute__((address_space(1))) unsigned int*)g,
      (__attribute__((address_space(3))) unsigned int*)l, 16, 0, 0);
}

#define MFMA(a, b, c) __builtin_amdgcn_mfma_f32_16x16x32_bf16((a), (b), (c), 0, 0, 0)

// ---------------- prep: split x, split Wqkv, cast Wp — one launch ----------------
__global__ __launch_bounds__(256) void k_prep(const float* __restrict__ x,
                                              const float* __restrict__ Wqkv,
                                              const float* __restrict__ Wp,
                                              u16* __restrict__ xh, u16* __restrict__ xl,
                                              u16* __restrict__ wh, u16* __restrict__ wl,
                                              u16* __restrict__ wpb) {
  const int blk = blockIdx.x, t = threadIdx.x;
  if (blk < 3072) {                       // split x: 786432 float4 groups
    int i = blk * 256 + t;
    float4 v = ((const float4*)x)[i];
    ushort4 h = make_ushort4(f2bf(v.x), f2bf(v.y), f2bf(v.z), f2bf(v.w));
    ushort4 l = make_ushort4(f2bf(v.x - bf2f(h.x)), f2bf(v.y - bf2f(h.y)),
                             f2bf(v.z - bf2f(h.z)), f2bf(v.w - bf2f(h.w)));
    ((ushort4*)xh)[i] = h;
    ((ushort4*)xl)[i] = l;
  } else if (blk < 4800) {                // split Wqkv: 442368 groups
    int i = (blk - 3072) * 256 + t;
    float4 v = ((const float4*)Wqkv)[i];
    ushort4 h = make_ushort4(f2bf(v.x), f2bf(v.y), f2bf(v.z), f2bf(v.w));
    ushort4 l = make_ushort4(f2bf(v.x - bf2f(h.x)), f2bf(v.y - bf2f(h.y)),
                             f2bf(v.z - bf2f(h.z)), f2bf(v.w - bf2f(h.w)));
    ((ushort4*)wh)[i] = h;
    ((ushort4*)wl)[i] = l;
  } else {                                // cast Wp: 147456 groups
    int i = (blk - 4800) * 256 + t;
    float4 v = ((const float4*)Wp)[i];
    ((ushort4*)wpb)[i] = make_ushort4(f2bf(v.x), f2bf(v.y), f2bf(v.z), f2bf(v.w));
  }
}

// ---------------- K1: qkv(hi,lo) = x @ Wqkv^T, split-bf16, async16 staged ----------------
// M=4096 N=2304 K=768. V cols (n0>=1536) computed plain-bf16 (1 MFMA, hi only).
__global__ __launch_bounds__(256) void k_qkv_mm3(const u16* __restrict__ Axh,
                                                 const u16* __restrict__ Axl,
                                                 const u16* __restrict__ Bwh,
                                                 const u16* __restrict__ Bwl,
                                                 u16* __restrict__ Chi,
                                                 u16* __restrict__ Clo) {
  __shared__ u16 Ah[128 * 32], Al[128 * 32], Bh[128 * 32], Bl[128 * 32];
  const int t = threadIdx.x, lane = t & 63, wave = t >> 6;
  const int wm = wave >> 1, wn = wave & 1;
  const int quad = lane >> 4, l16 = lane & 15;
  const int m0 = blockIdx.y * 128, n0 = blockIdx.x * 128;
  const int srow = t >> 2, sch = (t & 3) * 8;
  const bool vblk = (n0 >= 1536);   // V third: plain bf16 suffices
  f32x4 acc[4][4];
#pragma unroll
  for (int i = 0; i < 4; ++i)
#pragma unroll
    for (int j = 0; j < 4; ++j) acc[i][j] = (f32x4){0.f, 0.f, 0.f, 0.f};
  for (int k0 = 0; k0 < 768; k0 += 32) {
    const size_t ga = (size_t)(m0 + srow) * 768 + k0 + sch;
    const size_t gb = (size_t)(n0 + srow) * 768 + k0 + sch;
    __syncthreads();
    async16(Axh + ga, &Ah[t * 8]);
    async16(Axh + ga + (size_t)64 * 768, &Ah[2048 + t * 8]);
    async16(Bwh + gb, &Bh[t * 8]);
    async16(Bwh + gb + (size_t)64 * 768, &Bh[2048 + t * 8]);
    if (!vblk) {
      async16(Axl + ga, &Al[t * 8]);
      async16(Axl + ga + (size_t)64 * 768, &Al[2048 + t * 8]);
      async16(Bwl + gb, &Bl[t * 8]);
      async16(Bwl + gb + (size_t)64 * 768, &Bl[2048 + t * 8]);
    }
    __syncthreads();
    bf16x8 afh[4], afl[4], bfh[4], bfl[4];
#pragma unroll
    for (int i = 0; i < 4; ++i) {
      const int ro = (wm * 64 + i * 16 + l16) * 32 + quad * 8;
      afh[i] = *(const bf16x8*)&Ah[ro];
    }
#pragma unroll
    for (int j = 0; j < 4; ++j) {
      const int ro = (wn * 64 + j * 16 + l16) * 32 + quad * 8;
      bfh[j] = *(const bf16x8*)&Bh[ro];
    }
    if (!vblk) {
#pragma unroll
      for (int i = 0; i < 4; ++i) afl[i] = *(const bf16x8*)&Al[(wm * 64 + i * 16 + l16) * 32 + quad * 8];
#pragma unroll
      for (int j = 0; j < 4; ++j) bfl[j] = *(const bf16x8*)&Bl[(wn * 64 + j * 16 + l16) * 32 + quad * 8];
#pragma unroll
      for (int i = 0; i < 4; ++i)
#pragma unroll
        for (int j = 0; j < 4; ++j) {
          acc[i][j] = MFMA(afh[i], bfh[j], acc[i][j]);
          acc[i][j] = MFMA(afh[i], bfl[j], acc[i][j]);
          acc[i][j] = MFMA(afl[i], bfh[j], acc[i][j]);
        }
    } else {
#pragma unroll
      for (int i = 0; i < 4; ++i)
#pragma unroll
        for (int j = 0; j < 4; ++j) acc[i][j] = MFMA(afh[i], bfh[j], acc[i][j]);
    }
  }
#pragma unroll
  for (int i = 0; i < 4; ++i)
#pragma unroll
    for (int j = 0; j < 4; ++j)
#pragma unroll
      for (int r = 0; r < 4; ++r) {
        const int row = m0 + wm * 64 + i * 16 + quad * 4 + r;
        const int col = n0 + wn * 64 + j * 16 + l16;
        const float v = acc[i][j][r];
        const u16 hi = f2bf(v);
        Chi[(size_t)row * 2304 + col] = hi;
        if (!vblk) Clo[(size_t)row * 2304 + col] = f2bf(v - bf2f(hi));
      }
}

// ---------------- K1b: vT[bh][e][s] = qkv_hi[b,s,1536+h*64+e] ----------------
__global__ __launch_bounds__(256) void k_vt(const u16* __restrict__ qkvb,
                                            u16* __restrict__ vT) {
  __shared__ u16 tile[64][68];
  const int t = threadIdx.x;
  const int s0 = blockIdx.x * 64, bh = blockIdx.y;
  const int b = bh / 12, h = bh % 12;
  const u16* src = qkvb + ((size_t)(b * 1024 + s0)) * 2304 + 1536 + h * 64;
#pragma unroll
  for (int p = 0; p < 4; ++p) {
    int r = p * 16 + (t >> 4), c = (t & 15) * 4;
    *(ushort4*)&tile[r][c] = *(const ushort4*)&src[(size_t)r * 2304 + c];
  }
  __syncthreads();
  u16* dst = vT + ((size_t)bh * 64) * 1024 + s0;
#pragma unroll
  for (int p = 0; p < 4; ++p) {
    int e = p * 16 + (t >> 4), sc = (t & 15) * 4;
    ushort4 o = make_ushort4(tile[sc + 0][e], tile[sc + 1][e], tile[sc + 2][e], tile[sc + 3][e]);
    *(ushort4*)&dst[(size_t)e * 1024 + sc] = o;
  }
}

// ---------------- K2: scores(fp16) = Q @ K^T per (b,h), split-bf16 ----------------
__global__ __launch_bounds__(256) void k_qk_split(const u16* __restrict__ qhi,
                                                  const u16* __restrict__ qlo,
                                                  __half* __restrict__ scores) {
  __shared__ u16 Ah[128 * 32], Al[128 * 32], Bh[128 * 32], Bl[128 * 32];
  const int t = threadIdx.x, lane = t & 63, wave = t >> 6;
  const int wm = wave >> 1, wn = wave & 1;
  const int quad = lane >> 4, l16 = lane & 15;
  const int bh = blockIdx.z, b = bh / 12, h = bh % 12;
  const int m0 = blockIdx.y * 128, n0 = blockIdx.x * 128;
  const int srow = t >> 2, sch = (t & 3) * 8;
  const size_t qoff = (size_t)b * 1024 * 2304 + h * 64;
  __half* C = scores + ((size_t)bh << 20);
  f32x4 acc[4][4];
#pragma unroll
  for (int i = 0; i < 4; ++i)
#pragma unroll
    for (int j = 0; j < 4; ++j) acc[i][j] = (f32x4){0.f, 0.f, 0.f, 0.f};
  for (int k0 = 0; k0 < 64; k0 += 32) {
    const size_t ga = qoff + (size_t)(m0 + srow) * 2304 + k0 + sch;
    const size_t gb = qoff + 768 + (size_t)(n0 + srow) * 2304 + k0 + sch;
    __syncthreads();
    async16(qhi + ga, &Ah[t * 8]);
    async16(qhi + ga + (size_t)64 * 2304, &Ah[2048 + t * 8]);
    async16(qlo + ga, &Al[t * 8]);
    async16(qlo + ga + (size_t)64 * 2304, &Al[2048 + t * 8]);
    async16(qhi + gb, &Bh[t * 8]);
    async16(qhi + gb + (size_t)64 * 2304, &Bh[2048 + t * 8]);
    async16(qlo + gb, &Bl[t * 8]);
    async16(qlo + gb + (size_t)64 * 2304, &Bl[2048 + t * 8]);
    __syncthreads();
    bf16x8 afh[4], afl[4], bfh[4], bfl[4];
#pragma unroll
    for (int i = 0; i < 4; ++i) {
      const int ro = (wm * 64 + i * 16 + l16) * 32 + quad * 8;
      afh[i] = *(const bf16x8*)&Ah[ro];
      afl[i] = *(const bf16x8*)&Al[ro];
    }
#pragma unroll
    for (int j = 0; j < 4; ++j) {
      const int ro = (wn * 64 + j * 16 + l16) * 32 + quad * 8;
      bfh[j] = *(const bf16x8*)&Bh[ro];
      bfl[j] = *(const bf16x8*)&Bl[ro];
    }
#pragma unroll
    for (int i = 0; i < 4; ++i)
#pragma unroll
      for (int j = 0; j < 4; ++j) {
        acc[i][j] = MFMA(afh[i], bfh[j], acc[i][j]);
        acc[i][j] = MFMA(afh[i], bfl[j], acc[i][j]);
        acc[i][j] = MFMA(afl[i], bfh[j], acc[i][j]);
      }
  }
#pragma unroll
  for (int i = 0; i < 4; ++i)
#pragma unroll
    for (int j = 0; j < 4; ++j)
#pragma unroll
      for (int r = 0; r < 4; ++r) {
        const int row = m0 + wm * 64 + i * 16 + quad * 4 + r;
        const int col = n0 + wn * 64 + j * 16 + l16;
        C[(size_t)row * 1024 + col] = __float2half(acc[i][j][r]);
      }
}

// ---------------- K3: mix1 -> softmax -> mix2; fp16 in, bf16 out, in place ----------------
// One block per (b,q); thread owns k in [4t, 4t+4) (contiguous, 8B loads/stores).
// Mix FMAs as float2 ext-vectors -> v_pk_fma_f32.
__global__ __launch_bounds__(256) void k_mix(u16* __restrict__ scbuf,
                                             const float* __restrict__ Wl,
                                             const float* __restrict__ bl,
                                             const float* __restrict__ Ww,
                                             const float* __restrict__ bw) {
  __shared__ float wl_s[144], ww_s[144], bl_s[12], bw_s[12];
  __shared__ float red[4][12];
  const int t = threadIdx.x, lane = t & 63, wave = t >> 6;
  const int bq = blockIdx.x, b = bq >> 10, q = bq & 1023;
  if (t < 144) { wl_s[t] = Wl[t]; ww_s[t] = Ww[t]; }
  if (t < 12)  { bl_s[t] = bl[t]; bw_s[t] = bw[t]; }
  const size_t rowbase = (((size_t)b * 12 * 1024 + q) << 10) + 4 * t;  // + h<<20
  f32x2 raw[12][2];
#pragma unroll
  for (int h = 0; h < 12; ++h) {
    const __half* p = (const __half*)scbuf + rowbase + ((size_t)h << 20);
    uint2 u = *(const uint2*)p;
    __half2 h01 = __builtin_bit_cast(__half2, u.x);
    __half2 h23 = __builtin_bit_cast(__half2, u.y);
    float2 f01 = __half22float2(h01), f23 = __half22float2(h23);
    raw[h][0] = (f32x2){f01.x, f01.y};
    raw[h][1] = (f32x2){f23.x, f23.y};
  }
  __syncthreads();
  // mix1 (pk-fma)
  f32x2 lg[12][2];
#pragma unroll
  for (int g = 0; g < 12; ++g) {
    f32x2 a0 = {bl_s[g], bl_s[g]}, a1 = a0;
#pragma unroll
    for (int h = 0; h < 12; ++h) {
      const float wv = wl_s[g * 12 + h];
      const f32x2 w = {wv, wv};
      a0 = __builtin_elementwise_fma(w, raw[h][0], a0);
      a1 = __builtin_elementwise_fma(w, raw[h][1], a1);
    }
    lg[g][0] = a0; lg[g][1] = a1;
  }
  // row max
  float mx[12];
#pragma unroll
  for (int g = 0; g < 12; ++g) {
    f32x2 m2 = __builtin_elementwise_max(lg[g][0], lg[g][1]);
    mx[g] = fmaxf(m2.x, m2.y);
  }
#pragma unroll
  for (int off = 32; off > 0; off >>= 1)
#pragma unroll
    for (int g = 0; g < 12; ++g) mx[g] = fmaxf(mx[g], __shfl_xor(mx[g], off));
  if (lane == 0) {
#pragma unroll
    for (int g = 0; g < 12; ++g) red[wave][g] = mx[g];
  }
  __syncthreads();
#pragma unroll
  for (int g = 0; g < 12; ++g)
    mx[g] = fmaxf(fmaxf(red[0][g], red[1][g]), fmaxf(red[2][g], red[3][g]));
  // exp + row sum
  float sm[12];
#pragma unroll
  for (int g = 0; g < 12; ++g) {
    f32x2 e0, e1;
    e0.x = __expf(lg[g][0].x - mx[g]);
    e0.y = __expf(lg[g][0].y - mx[g]);
    e1.x = __expf(lg[g][1].x - mx[g]);
    e1.y = __expf(lg[g][1].y - mx[g]);
    lg[g][0] = e0; lg[g][1] = e1;
    f32x2 s2 = e0 + e1;
    sm[g] = s2.x + s2.y;
  }
#pragma unroll
  for (int off = 32; off > 0; off >>= 1)
#pragma unroll
    for (int g = 0; g < 12; ++g) sm[g] += __shfl_xor(sm[g], off);
  __syncthreads();  // red[] reuse
  if (lane == 0) {
#pragma unroll
    for (int g = 0; g < 12; ++g) red[wave][g] = sm[g];
  }
  __syncthreads();
#pragma unroll
  for (int g = 0; g < 12; ++g) {
    const float inv = 1.0f / (red[0][g] + red[1][g] + red[2][g] + red[3][g]);
    const f32x2 iv = {inv, inv};
    lg[g][0] *= iv;
    lg[g][1] *= iv;
  }
  // mix2 (pk-fma) + 8B stores, in place
#pragma unroll
  for (int g2 = 0; g2 < 12; ++g2) {
    f32x2 o0 = {bw_s[g2], bw_s[g2]}, o1 = o0;
#pragma unroll
    for (int h = 0; h < 12; ++h) {
      const float wv = ww_s[g2 * 12 + h];
      const f32x2 w = {wv, wv};
      o0 = __builtin_elementwise_fma(w, lg[h][0], o0);
      o1 = __builtin_elementwise_fma(w, lg[h][1], o1);
    }
    u16* p = scbuf + rowbase + ((size_t)g2 << 20);
    *(ushort4*)p = make_ushort4(f2bf(o0.x), f2bf(o0.y), f2bf(o1.x), f2bf(o1.y));
  }
}

// ---------------- K4: ctx = P(bf16) @ V per (b,h), pure async16 GEMM ----------------
// M=1024 N=64 K=1024; BM=128 BN=64; waves 2x2, each 64x32 (4x2 frags)
__global__ __launch_bounds__(256) void k_pv(const u16* __restrict__ probs,
                                            const u16* __restrict__ vT,
                                            u16* __restrict__ ctx) {
  __shared__ u16 As[128 * 32];
  __shared__ u16 Bs[64 * 32];
  const int t = threadIdx.x, lane = t & 63, wave = t >> 6;
  const int wm = wave >> 1, wn = wave & 1;
  const int quad = lane >> 4, l16 = lane & 15;
  const int bh = blockIdx.y, b = bh / 12, h = bh % 12;
  const int m0 = blockIdx.x * 128;
  const u16* P = probs + ((size_t)bh << 20);
  const u16* V = vT + (size_t)bh * 64 * 1024;
  const int srow = t >> 2, sch = (t & 3) * 8;
  f32x4 acc[4][2];
#pragma unroll
  for (int i = 0; i < 4; ++i)
#pragma unroll
    for (int j = 0; j < 2; ++j) acc[i][j] = (f32x4){0.f, 0.f, 0.f, 0.f};
  for (int k0 = 0; k0 < 1024; k0 += 32) {
    __syncthreads();
    const u16* ga = P + (size_t)(m0 + srow) * 1024 + k0 + sch;
    async16(ga, &As[t * 8]);
    async16(ga + (size_t)64 * 1024, &As[2048 + t * 8]);
    async16(V + (size_t)srow * 1024 + k0 + sch, &Bs[t * 8]);
    __syncthreads();
    bf16x8 af[4], bfr[2];
#pragma unroll
    for (int i = 0; i < 4; ++i) af[i] = *(const bf16x8*)&As[(wm * 64 + i * 16 + l16) * 32 + quad * 8];
#pragma unroll
    for (int j = 0; j < 2; ++j) bfr[j] = *(const bf16x8*)&Bs[(wn * 32 + j * 16 + l16) * 32 + quad * 8];
#pragma unroll
    for (int i = 0; i < 4; ++i)
#pragma unroll
      for (int j = 0; j < 2; ++j) acc[i][j] = MFMA(af[i], bfr[j], acc[i][j]);
  }
#pragma unroll
  for (int i = 0; i < 4; ++i)
#pragma unroll
    for (int j = 0; j < 2; ++j)
#pragma unroll
      for (int r = 0; r < 4; ++r) {
        int q = m0 + wm * 64 + i * 16 + quad * 4 + r;
        int e = wn * 32 + j * 16 + l16;
        ctx[(size_t)(b * 1024 + q) * 768 + h * 64 + e] = f2bf(acc[i][j][r]);
      }
}

// ---------------- K5: out = ctx @ Wp^T + bp, pure async16 GEMM ----------------
// M=4096 N=768 K=768
__global__ __launch_bounds__(256) void k_oproj(const u16* __restrict__ A,
                                               const u16* __restrict__ Bm,
                                               const float* __restrict__ bp,
                                               float* __restrict__ out) {
  __shared__ u16 As[128 * 32];
  __shared__ u16 Bs[128 * 32];
  const int t = threadIdx.x, lane = t & 63, wave = t >> 6;
  const int wm = wave >> 1, wn = wave & 1;
  const int quad = lane >> 4, l16 = lane & 15;
  const int m0 = blockIdx.y * 128, n0 = blockIdx.x * 128;
  const int srow = t >> 2, sch = (t & 3) * 8;
  f32x4 acc[4][4];
#pragma unroll
  for (int i = 0; i < 4; ++i)
#pragma unroll
    for (int j = 0; j < 4; ++j) acc[i][j] = (f32x4){0.f, 0.f, 0.f, 0.f};
  for (int k0 = 0; k0 < 768; k0 += 32) {
    __syncthreads();
    const u16* ga = A + (size_t)(m0 + srow) * 768 + k0 + sch;
    const u16* gb = Bm + (size_t)(n0 + srow) * 768 + k0 + sch;
    async16(ga, &As[t * 8]);
    async16(ga + (size_t)64 * 768, &As[2048 + t * 8]);
    async16(gb, &Bs[t * 8]);
    async16(gb + (size_t)64 * 768, &Bs[2048 + t * 8]);
    __syncthreads();
    bf16x8 af[4], bfr[4];
#pragma unroll
    for (int i = 0; i < 4; ++i) af[i] = *(const bf16x8*)&As[(wm * 64 + i * 16 + l16) * 32 + quad * 8];
#pragma unroll
    for (int j = 0; j < 4; ++j) bfr[j] = *(const bf16x8*)&Bs[(wn * 64 + j * 16 + l16) * 32 + quad * 8];
#pragma unroll
    for (int i = 0; i < 4; ++i)
#pragma unroll
      for (int j = 0; j < 4; ++j) acc[i][j] = MFMA(af[i], bfr[j], acc[i][j]);
  }
#pragma unroll
  for (int i = 0; i < 4; ++i)
#pragma unroll
    for (int j = 0; j < 4; ++j)
#pragma unroll
      for (int r = 0; r < 4; ++r) {
        const int row = m0 + wm * 64 + i * 16 + quad * 4 + r;
        const int col = n0 + wn * 64 + j * 16 + l16;
        out[(size_t)row * 768 + col] = acc[i][j][r] + bp[col];
      }
}

extern "C" void kernel_launch(void* const* d_in, const int* in_sizes, int n_in,
                              void* d_out, int out_size, void* d_ws, size_t ws_size,
                              hipStream_t stream) {
  const float* x    = (const float*)d_in[0];
  const float* Wqkv = (const float*)d_in[1];
  const float* Wl   = (const float*)d_in[2];
  const float* bl   = (const float*)d_in[3];
  const float* Ww   = (const float*)d_in[4];
  const float* bw   = (const float*)d_in[5];
  const float* Wp   = (const float*)d_in[6];
  const float* bp   = (const float*)d_in[7];
  float* out = (float*)d_out;

  char* ws = (char*)d_ws;
  u16* scbuf  = (u16*)(ws + 0);               // 100,663,296 B
  u16* qkv_hi = (u16*)(ws + 100663296ull);
  u16* qkv_lo = (u16*)(ws + 119537664ull);
  u16* vT     = (u16*)(ws + 138412032ull);
  u16* ctx    = (u16*)(ws + 144703488ull);
  u16* x_hi   = (u16*)(ws + 150994944ull);
  u16* x_lo   = (u16*)(ws + 157286400ull);
  u16* wq_hi  = (u16*)(ws + 163577856ull);
  u16* wq_lo  = (u16*)(ws + 167116800ull);
  u16* wp_b   = (u16*)(ws + 170655744ull);

  hipLaunchKernelGGL(k_prep, dim3(5376), dim3(256), 0, stream,
                     x, Wqkv, Wp, x_hi, x_lo, wq_hi, wq_lo, wp_b);

  hipLaunchKernelGGL(k_qkv_mm3, dim3(18, 32),   dim3(256), 0, stream,
                     x_hi, x_lo, wq_hi, wq_lo, qkv_hi, qkv_lo);
  hipLaunchKernelGGL(k_vt,      dim3(16, 48),   dim3(256), 0, stream, qkv_hi, vT);
  hipLaunchKernelGGL(k_qk_split, dim3(8, 8, 48), dim3(256), 0, stream,
                     qkv_hi, qkv_lo, (__half*)scbuf);
  hipLaunchKernelGGL(k_mix,     dim3(4096),     dim3(256), 0, stream, scbuf, Wl, bl, Ww, bw);
  hipLaunchKernelGGL(k_pv,      dim3(8, 48),    dim3(256), 0, stream, scbuf, vT, ctx);
  hipLaunchKernelGGL(k_oproj,   dim3(6, 32),    dim3(256), 0, stream, ctx, wp_b, bp, out);
}

// Round 7
// 279.608 us; speedup vs baseline: 2.6004x; 1.0382x over previous
//
#include <hip/hip_runtime.h>
#include <math.h>

// B=4, S=1024, D=768, H=12, E=64, 3D=2304
// Workspace layout (bytes), total ~146.7 MB:
//   scbuf fp16 scores -> fp16 probs in place : 100,663,296 @ 0   [bh][q][k]
//   qkf  fp16 [4096][1536] (Q,K)  : 12,582,912 @ 100,663,296
//   vbuf fp16 [4096][768]  (V)    :  6,291,456 @ 113,246,208
//   ctx  fp16 [4096][768]         :  6,291,456 @ 119,537,664
//   x_hi bf16 :  6,291,456 @ 125,829,120
//   x_lo bf16 :  6,291,456 @ 132,120,576
//   wq_hi bf16:  3,538,944 @ 138,412,032
//   wq_lo bf16:  3,538,944 @ 141,950,976
//   wp_h fp16 :  1,179,648 @ 145,489,920

typedef __attribute__((ext_vector_type(8))) short bf16x8;
typedef _Float16 f16;
typedef __attribute__((ext_vector_type(8))) _Float16 f16x8;
typedef __attribute__((ext_vector_type(2))) _Float16 f16x2;
typedef __attribute__((ext_vector_type(4))) float f32x4;
typedef __attribute__((ext_vector_type(2))) float f32x2;
typedef unsigned short u16;

__device__ __forceinline__ u16 f2bf(float f) {
  unsigned u = __float_as_uint(f);
  return (u16)((u + 0x7fffu + ((u >> 16) & 1u)) >> 16);
}
__device__ __forceinline__ float bf2f(u16 h) {
  return __uint_as_float(((unsigned)h) << 16);
}
__device__ __forceinline__ u16 f2h(float f) {
  f16 h = (f16)f;
  return __builtin_bit_cast(u16, h);
}
__device__ __forceinline__ unsigned pk2h(float a, float b) {
  return __builtin_bit_cast(unsigned, __builtin_amdgcn_cvt_pkrtz(a, b));
}

__device__ __forceinline__ void async16(const void* g, void* l) {
  __builtin_amdgcn_global_load_lds(
      (const __attribute__((address_space(1))) unsigned int*)g,
      (__attribute__((address_space(3))) unsigned int*)l, 16, 0, 0);
}

#define MFMA_BF(a, b, c) __builtin_amdgcn_mfma_f32_16x16x32_bf16((a), (b), (c), 0, 0, 0)
#define MFMA_F16(a, b, c) __builtin_amdgcn_mfma_f32_16x16x32_f16((a), (b), (c), 0, 0, 0)

// ---------------- prep: split x, split Wqkv (bf16 hi/lo), cast Wp (fp16) ----------------
__global__ __launch_bounds__(256) void k_prep(const float* __restrict__ x,
                                              const float* __restrict__ Wqkv,
                                              const float* __restrict__ Wp,
                                              u16* __restrict__ xh, u16* __restrict__ xl,
                                              u16* __restrict__ wh, u16* __restrict__ wl,
                                              u16* __restrict__ wph) {
  const int blk = blockIdx.x, t = threadIdx.x;
  if (blk < 3072) {
    int i = blk * 256 + t;
    float4 v = ((const float4*)x)[i];
    ushort4 h = make_ushort4(f2bf(v.x), f2bf(v.y), f2bf(v.z), f2bf(v.w));
    ushort4 l = make_ushort4(f2bf(v.x - bf2f(h.x)), f2bf(v.y - bf2f(h.y)),
                             f2bf(v.z - bf2f(h.z)), f2bf(v.w - bf2f(h.w)));
    ((ushort4*)xh)[i] = h;
    ((ushort4*)xl)[i] = l;
  } else if (blk < 4800) {
    int i = (blk - 3072) * 256 + t;
    float4 v = ((const float4*)Wqkv)[i];
    ushort4 h = make_ushort4(f2bf(v.x), f2bf(v.y), f2bf(v.z), f2bf(v.w));
    ushort4 l = make_ushort4(f2bf(v.x - bf2f(h.x)), f2bf(v.y - bf2f(h.y)),
                             f2bf(v.z - bf2f(h.z)), f2bf(v.w - bf2f(h.w)));
    ((ushort4*)wh)[i] = h;
    ((ushort4*)wl)[i] = l;
  } else {
    int i = (blk - 4800) * 256 + t;
    float4 v = ((const float4*)Wp)[i];
    ((ushort4*)wph)[i] = make_ushort4(f2h(v.x), f2h(v.y), f2h(v.z), f2h(v.w));
  }
}

// ---------------- K1: qkv = x @ Wqkv^T, split-bf16 input (3 MFMA), fp16 out ----------------
// M=4096 N=2304 K=768. Q,K cols -> qkf[4096][1536]; V cols (n0>=1536, 1 MFMA) -> vbuf[4096][768].
__global__ __launch_bounds__(256) void k_qkv(const u16* __restrict__ Axh,
                                             const u16* __restrict__ Axl,
                                             const u16* __restrict__ Bwh,
                                             const u16* __restrict__ Bwl,
                                             u16* __restrict__ qkf,
                                             u16* __restrict__ vbuf) {
  __shared__ u16 smem[4][4096];   // Ah, Al, Bh, Bl; reused as 128x128 repack tile
  u16* Ah = smem[0]; u16* Al = smem[1]; u16* Bh = smem[2]; u16* Bl = smem[3];
  const int t = threadIdx.x, lane = t & 63, wave = t >> 6;
  const int wm = wave >> 1, wn = wave & 1;
  const int quad = lane >> 4, l16 = lane & 15;
  const int m0 = blockIdx.y * 128, n0 = blockIdx.x * 128;
  const bool vblk = (n0 >= 1536);
  f32x4 acc[4][4];
#pragma unroll
  for (int i = 0; i < 4; ++i)
#pragma unroll
    for (int j = 0; j < 4; ++j) acc[i][j] = (f32x4){0.f, 0.f, 0.f, 0.f};
  const int srow = t >> 2, sch = (t & 3) * 8;
  for (int k0 = 0; k0 < 768; k0 += 32) {
    const size_t ga = (size_t)(m0 + srow) * 768 + k0 + sch;
    const size_t gb = (size_t)(n0 + srow) * 768 + k0 + sch;
    __syncthreads();
    async16(Axh + ga, &Ah[t * 8]);
    async16(Axh + ga + (size_t)64 * 768, &Ah[2048 + t * 8]);
    async16(Bwh + gb, &Bh[t * 8]);
    async16(Bwh + gb + (size_t)64 * 768, &Bh[2048 + t * 8]);
    if (!vblk) {
      async16(Axl + ga, &Al[t * 8]);
      async16(Axl + ga + (size_t)64 * 768, &Al[2048 + t * 8]);
      async16(Bwl + gb, &Bl[t * 8]);
      async16(Bwl + gb + (size_t)64 * 768, &Bl[2048 + t * 8]);
    }
    __syncthreads();
    bf16x8 afh[4], afl[4], bfh[4], bfl[4];
#pragma unroll
    for (int i = 0; i < 4; ++i) afh[i] = *(const bf16x8*)&Ah[(wm * 64 + i * 16 + l16) * 32 + quad * 8];
#pragma unroll
    for (int j = 0; j < 4; ++j) bfh[j] = *(const bf16x8*)&Bh[(wn * 64 + j * 16 + l16) * 32 + quad * 8];
    if (!vblk) {
#pragma unroll
      for (int i = 0; i < 4; ++i) afl[i] = *(const bf16x8*)&Al[(wm * 64 + i * 16 + l16) * 32 + quad * 8];
#pragma unroll
      for (int j = 0; j < 4; ++j) bfl[j] = *(const bf16x8*)&Bl[(wn * 64 + j * 16 + l16) * 32 + quad * 8];
#pragma unroll
      for (int i = 0; i < 4; ++i)
#pragma unroll
        for (int j = 0; j < 4; ++j) {
          acc[i][j] = MFMA_BF(afh[i], bfh[j], acc[i][j]);
          acc[i][j] = MFMA_BF(afh[i], bfl[j], acc[i][j]);
          acc[i][j] = MFMA_BF(afl[i], bfh[j], acc[i][j]);
        }
    } else {
#pragma unroll
      for (int i = 0; i < 4; ++i)
#pragma unroll
        for (int j = 0; j < 4; ++j) acc[i][j] = MFMA_BF(afh[i], bfh[j], acc[i][j]);
    }
  }
  // epilogue: repack via LDS, coalesced 16B stores
  __syncthreads();
  u16* T = &smem[0][0];
#pragma unroll
  for (int i = 0; i < 4; ++i)
#pragma unroll
    for (int j = 0; j < 4; ++j)
#pragma unroll
      for (int r = 0; r < 4; ++r)
        T[(wm * 64 + i * 16 + quad * 4 + r) * 128 + wn * 64 + j * 16 + l16] = f2h(acc[i][j][r]);
  __syncthreads();
  const int row = t >> 1, half = t & 1;
  const u16* src = &T[row * 128 + half * 64];
  if (!vblk) {
    u16* dst = qkf + (size_t)(m0 + row) * 1536 + n0 + half * 64;
#pragma unroll
    for (int c = 0; c < 64; c += 8) *(uint4*)(dst + c) = *(const uint4*)(src + c);
  } else {
    u16* dst = vbuf + (size_t)(m0 + row) * 768 + (n0 - 1536) + half * 64;
#pragma unroll
    for (int c = 0; c < 64; c += 8) *(uint4*)(dst + c) = *(const uint4*)(src + c);
  }
}

// ---------------- K2: scores(fp16) = Q @ K^T per (b,h), single fp16 MFMA ----------------
__global__ __launch_bounds__(256) void k_qk(const u16* __restrict__ qkf,
                                            u16* __restrict__ scbuf) {
  __shared__ u16 smem[4][4096];   // [0]=A stage, [1]=B stage; all 4 = repack tile
  u16* As = smem[0]; u16* Bs = smem[1];
  const int t = threadIdx.x, lane = t & 63, wave = t >> 6;
  const int wm = wave >> 1, wn = wave & 1;
  const int quad = lane >> 4, l16 = lane & 15;
  const int bh = blockIdx.z, b = bh / 12, h = bh % 12;
  const int m0 = blockIdx.y * 128, n0 = blockIdx.x * 128;
  const int srow = t >> 2, sch = (t & 3) * 8;
  u16* C = scbuf + ((size_t)bh << 20);
  f32x4 acc[4][4];
#pragma unroll
  for (int i = 0; i < 4; ++i)
#pragma unroll
    for (int j = 0; j < 4; ++j) acc[i][j] = (f32x4){0.f, 0.f, 0.f, 0.f};
  for (int k0 = 0; k0 < 64; k0 += 32) {
    const size_t ga = (size_t)(b * 1024 + m0 + srow) * 1536 + h * 64 + k0 + sch;
    const size_t gb = (size_t)(b * 1024 + n0 + srow) * 1536 + 768 + h * 64 + k0 + sch;
    __syncthreads();
    async16(qkf + ga, &As[t * 8]);
    async16(qkf + ga + (size_t)64 * 1536, &As[2048 + t * 8]);
    async16(qkf + gb, &Bs[t * 8]);
    async16(qkf + gb + (size_t)64 * 1536, &Bs[2048 + t * 8]);
    __syncthreads();
    f16x8 af[4], bfr[4];
#pragma unroll
    for (int i = 0; i < 4; ++i) af[i] = *(const f16x8*)&As[(wm * 64 + i * 16 + l16) * 32 + quad * 8];
#pragma unroll
    for (int j = 0; j < 4; ++j) bfr[j] = *(const f16x8*)&Bs[(wn * 64 + j * 16 + l16) * 32 + quad * 8];
#pragma unroll
    for (int i = 0; i < 4; ++i)
#pragma unroll
      for (int j = 0; j < 4; ++j) acc[i][j] = MFMA_F16(af[i], bfr[j], acc[i][j]);
  }
  __syncthreads();
  u16* T = &smem[0][0];
#pragma unroll
  for (int i = 0; i < 4; ++i)
#pragma unroll
    for (int j = 0; j < 4; ++j)
#pragma unroll
      for (int r = 0; r < 4; ++r)
        T[(wm * 64 + i * 16 + quad * 4 + r) * 128 + wn * 64 + j * 16 + l16] = f2h(acc[i][j][r]);
  __syncthreads();
  const int row = t >> 1, half = t & 1;
  const u16* src = &T[row * 128 + half * 64];
  u16* dst = C + (size_t)(m0 + row) * 1024 + n0 + half * 64;
#pragma unroll
  for (int c = 0; c < 64; c += 8) *(uint4*)(dst + c) = *(const uint4*)(src + c);
}

// ---------------- K3: mix1 -> constant-shift softmax -> mix2; fp16 in/out, in place ----------------
__global__ __launch_bounds__(256) void k_mix(u16* __restrict__ scbuf,
                                             const float* __restrict__ Wl,
                                             const float* __restrict__ bl,
                                             const float* __restrict__ Ww,
                                             const float* __restrict__ bw) {
  __shared__ float wl_s[144], ww_s[144], bl_s[12], bw_s[12];
  __shared__ float red[4][12];
  const int t = threadIdx.x, lane = t & 63, wave = t >> 6;
  const int bq = blockIdx.x, b = bq >> 10, q = bq & 1023;
  if (t < 144) { wl_s[t] = Wl[t]; ww_s[t] = Ww[t]; }
  if (t < 12)  { bl_s[t] = bl[t]; bw_s[t] = bw[t]; }
  const size_t rowbase = (((size_t)b * 12 * 1024 + q) << 10) + 4 * t;  // + h<<20
  f32x2 raw[12][2];
#pragma unroll
  for (int h = 0; h < 12; ++h) {
    const u16* p = scbuf + rowbase + ((size_t)h << 20);
    uint2 u = *(const uint2*)p;
    f16x2 a01 = __builtin_bit_cast(f16x2, u.x);
    f16x2 a23 = __builtin_bit_cast(f16x2, u.y);
    raw[h][0] = (f32x2){(float)a01.x, (float)a01.y};
    raw[h][1] = (f32x2){(float)a23.x, (float)a23.y};
  }
  __syncthreads();
  // mix1 (pk-fma), bias pre-shifted by -16 (constant-shift softmax)
  f32x2 lg[12][2];
#pragma unroll
  for (int g = 0; g < 12; ++g) {
    f32x2 a0 = {bl_s[g] - 16.f, bl_s[g] - 16.f}, a1 = a0;
#pragma unroll
    for (int h = 0; h < 12; ++h) {
      const float wv = wl_s[g * 12 + h];
      const f32x2 w = {wv, wv};
      a0 = __builtin_elementwise_fma(w, raw[h][0], a0);
      a1 = __builtin_elementwise_fma(w, raw[h][1], a1);
    }
    lg[g][0] = a0; lg[g][1] = a1;
  }
  // exp + row sum (no max pass: exp(l-16) safe, |logit| << 104)
  float sm[12];
#pragma unroll
  for (int g = 0; g < 12; ++g) {
    f32x2 e0, e1;
    e0.x = __expf(lg[g][0].x); e0.y = __expf(lg[g][0].y);
    e1.x = __expf(lg[g][1].x); e1.y = __expf(lg[g][1].y);
    lg[g][0] = e0; lg[g][1] = e1;
    f32x2 s2 = e0 + e1;
    sm[g] = s2.x + s2.y;
  }
#pragma unroll
  for (int off = 32; off > 0; off >>= 1)
#pragma unroll
    for (int g = 0; g < 12; ++g) sm[g] += __shfl_xor(sm[g], off);
  if (lane == 0) {
#pragma unroll
    for (int g = 0; g < 12; ++g) red[wave][g] = sm[g];
  }
  __syncthreads();
#pragma unroll
  for (int g = 0; g < 12; ++g) {
    const float inv = 1.0f / (red[0][g] + red[1][g] + red[2][g] + red[3][g]);
    const f32x2 iv = {inv, inv};
    lg[g][0] *= iv;
    lg[g][1] *= iv;
  }
  // mix2 (pk-fma) + fp16 pack stores, in place
#pragma unroll
  for (int g2 = 0; g2 < 12; ++g2) {
    f32x2 o0 = {bw_s[g2], bw_s[g2]}, o1 = o0;
#pragma unroll
    for (int h = 0; h < 12; ++h) {
      const float wv = ww_s[g2 * 12 + h];
      const f32x2 w = {wv, wv};
      o0 = __builtin_elementwise_fma(w, lg[h][0], o0);
      o1 = __builtin_elementwise_fma(w, lg[h][1], o1);
    }
    uint2 st = make_uint2(pk2h(o0.x, o0.y), pk2h(o1.x, o1.y));
    *(uint2*)(scbuf + rowbase + ((size_t)g2 << 20)) = st;
  }
}

// ---------------- K4: ctx = P(fp16) @ V(fp16) per (b,h); V transposed in-LDS ----------------
// M=1024 N=64 K=1024; BM=128; waves 2x2, each 64x32 (4x2 frags)
__global__ __launch_bounds__(256) void k_pv(const u16* __restrict__ probs,
                                            const u16* __restrict__ vbuf,
                                            u16* __restrict__ ctx) {
  __shared__ u16 As[4096];      // 128x32 P tile
  __shared__ u16 Bs[64 * 40];   // V^T tile: [e][s-chunk 32], row stride 40 (16B-aligned)
  const int t = threadIdx.x, lane = t & 63, wave = t >> 6;
  const int wm = wave >> 1, wn = wave & 1;
  const int quad = lane >> 4, l16 = lane & 15;
  const int bh = blockIdx.y, b = bh / 12, h = bh % 12;
  const int m0 = blockIdx.x * 128;
  const u16* P = probs + ((size_t)bh << 20);
  const int srow = t >> 2, sch = (t & 3) * 8;
  const int ev = t & 63, s8 = (t >> 6) * 8;   // V transpose-load: e=ev, s-chunk s8
  f32x4 acc[4][2];
#pragma unroll
  for (int i = 0; i < 4; ++i)
#pragma unroll
    for (int j = 0; j < 2; ++j) acc[i][j] = (f32x4){0.f, 0.f, 0.f, 0.f};
  for (int k0 = 0; k0 < 1024; k0 += 32) {
    // V column loads into regs (coalesced per-inst: 64 lanes x 2B contiguous)
    const u16* vp = vbuf + (size_t)(b * 1024 + k0 + s8) * 768 + h * 64 + ev;
    u16 vcol[8];
#pragma unroll
    for (int i = 0; i < 8; ++i) vcol[i] = vp[(size_t)i * 768];
    __syncthreads();
    const u16* ga = P + (size_t)(m0 + srow) * 1024 + k0 + sch;
    async16(ga, &As[t * 8]);
    async16(ga + (size_t)64 * 1024, &As[2048 + t * 8]);
    *(ushort4*)&Bs[ev * 40 + s8] = make_ushort4(vcol[0], vcol[1], vcol[2], vcol[3]);
    *(ushort4*)&Bs[ev * 40 + s8 + 4] = make_ushort4(vcol[4], vcol[5], vcol[6], vcol[7]);
    __syncthreads();
    f16x8 af[4], bfr[2];
#pragma unroll
    for (int i = 0; i < 4; ++i) af[i] = *(const f16x8*)&As[(wm * 64 + i * 16 + l16) * 32 + quad * 8];
#pragma unroll
    for (int j = 0; j < 2; ++j) bfr[j] = *(const f16x8*)&Bs[(wn * 32 + j * 16 + l16) * 40 + quad * 8];
#pragma unroll
    for (int i = 0; i < 4; ++i)
#pragma unroll
      for (int j = 0; j < 2; ++j) acc[i][j] = MFMA_F16(af[i], bfr[j], acc[i][j]);
  }
#pragma unroll
  for (int i = 0; i < 4; ++i)
#pragma unroll
    for (int j = 0; j < 2; ++j)
#pragma unroll
      for (int r = 0; r < 4; ++r) {
        int q = m0 + wm * 64 + i * 16 + quad * 4 + r;
        int e = wn * 32 + j * 16 + l16;
        ctx[(size_t)(b * 1024 + q) * 768 + h * 64 + e] = f2h(acc[i][j][r]);
      }
}

// ---------------- K5: out = ctx @ Wp^T + bp (fp16 MFMA, fp32 out) ----------------
// M=4096 N=768 K=768
__global__ __launch_bounds__(256) void k_oproj(const u16* __restrict__ A,
                                               const u16* __restrict__ Bm,
                                               const float* __restrict__ bp,
                                               float* __restrict__ out) {
  __shared__ u16 As[4096];
  __shared__ u16 Bs[4096];
  const int t = threadIdx.x, lane = t & 63, wave = t >> 6;
  const int wm = wave >> 1, wn = wave & 1;
  const int quad = lane >> 4, l16 = lane & 15;
  const int m0 = blockIdx.y * 128, n0 = blockIdx.x * 128;
  const int srow = t >> 2, sch = (t & 3) * 8;
  f32x4 acc[4][4];
#pragma unroll
  for (int i = 0; i < 4; ++i)
#pragma unroll
    for (int j = 0; j < 4; ++j) acc[i][j] = (f32x4){0.f, 0.f, 0.f, 0.f};
  for (int k0 = 0; k0 < 768; k0 += 32) {
    __syncthreads();
    const u16* ga = A + (size_t)(m0 + srow) * 768 + k0 + sch;
    const u16* gb = Bm + (size_t)(n0 + srow) * 768 + k0 + sch;
    async16(ga, &As[t * 8]);
    async16(ga + (size_t)64 * 768, &As[2048 + t * 8]);
    async16(gb, &Bs[t * 8]);
    async16(gb + (size_t)64 * 768, &Bs[2048 + t * 8]);
    __syncthreads();
    f16x8 af[4], bfr[4];
#pragma unroll
    for (int i = 0; i < 4; ++i) af[i] = *(const f16x8*)&As[(wm * 64 + i * 16 + l16) * 32 + quad * 8];
#pragma unroll
    for (int j = 0; j < 4; ++j) bfr[j] = *(const f16x8*)&Bs[(wn * 64 + j * 16 + l16) * 32 + quad * 8];
#pragma unroll
    for (int i = 0; i < 4; ++i)
#pragma unroll
      for (int j = 0; j < 4; ++j) acc[i][j] = MFMA_F16(af[i], bfr[j], acc[i][j]);
  }
#pragma unroll
  for (int i = 0; i < 4; ++i)
#pragma unroll
    for (int j = 0; j < 4; ++j)
#pragma unroll
      for (int r = 0; r < 4; ++r) {
        const int row = m0 + wm * 64 + i * 16 + quad * 4 + r;
        const int col = n0 + wn * 64 + j * 16 + l16;
        out[(size_t)row * 768 + col] = acc[i][j][r] + bp[col];
      }
}

extern "C" void kernel_launch(void* const* d_in, const int* in_sizes, int n_in,
                              void* d_out, int out_size, void* d_ws, size_t ws_size,
                              hipStream_t stream) {
  const float* x    = (const float*)d_in[0];
  const float* Wqkv = (const float*)d_in[1];
  const float* Wl   = (const float*)d_in[2];
  const float* bl   = (const float*)d_in[3];
  const float* Ww   = (const float*)d_in[4];
  const float* bw   = (const float*)d_in[5];
  const float* Wp   = (const float*)d_in[6];
  const float* bp   = (const float*)d_in[7];
  float* out = (float*)d_out;

  char* ws = (char*)d_ws;
  u16* scbuf = (u16*)(ws + 0);               // 100,663,296 B
  u16* qkf   = (u16*)(ws + 100663296ull);    //  12,582,912 B
  u16* vbuf  = (u16*)(ws + 113246208ull);    //   6,291,456 B
  u16* ctx   = (u16*)(ws + 119537664ull);    //   6,291,456 B
  u16* x_hi  = (u16*)(ws + 125829120ull);    //   6,291,456 B
  u16* x_lo  = (u16*)(ws + 132120576ull);    //   6,291,456 B
  u16* wq_hi = (u16*)(ws + 138412032ull);    //   3,538,944 B
  u16* wq_lo = (u16*)(ws + 141950976ull);    //   3,538,944 B
  u16* wp_h  = (u16*)(ws + 145489920ull);    //   1,179,648 B

  hipLaunchKernelGGL(k_prep, dim3(5376), dim3(256), 0, stream,
                     x, Wqkv, Wp, x_hi, x_lo, wq_hi, wq_lo, wp_h);
  hipLaunchKernelGGL(k_qkv,  dim3(18, 32),   dim3(256), 0, stream,
                     x_hi, x_lo, wq_hi, wq_lo, qkf, vbuf);
  hipLaunchKernelGGL(k_qk,   dim3(8, 8, 48), dim3(256), 0, stream, qkf, scbuf);
  hipLaunchKernelGGL(k_mix,  dim3(4096),     dim3(256), 0, stream, scbuf, Wl, bl, Ww, bw);
  hipLaunchKernelGGL(k_pv,   dim3(8, 48),    dim3(256), 0, stream, scbuf, vbuf, ctx);
  hipLaunchKernelGGL(k_oproj, dim3(6, 32),   dim3(256), 0, stream, ctx, wp_h, bp, out);
}

// Round 8
// 249.587 us; speedup vs baseline: 2.9132x; 1.1203x over previous
//
#include <hip/hip_runtime.h>
#include <math.h>

// B=4, S=1024, D=768, H=12, E=64, 3D=2304
// Workspace layout (bytes), total ~137 MB:
//   scbuf fp16 scores -> fp16 probs in place : 100,663,296 @ 0   [bh][q][k]
//   qkf  fp16 [4096][1536] (Q,K)  : 12,582,912 @ 100,663,296
//   vbuf fp16 [4096][768]  (V)    :  6,291,456 @ 113,246,208
//   ctx  fp16 [4096][768]         :  6,291,456 @ 119,537,664
//   x_h  fp16 :  6,291,456 @ 125,829,120
//   wq_h fp16 :  3,538,944 @ 132,120,576
//   wp_h fp16 :  1,179,648 @ 135,659,520

typedef _Float16 f16;
typedef __attribute__((ext_vector_type(8))) _Float16 f16x8;
typedef __attribute__((ext_vector_type(2))) _Float16 f16x2;
typedef __attribute__((ext_vector_type(4))) float f32x4;
typedef __attribute__((ext_vector_type(2))) float f32x2;
typedef unsigned short u16;

__device__ __forceinline__ u16 f2h(float f) {      // RTN convert
  f16 h = (f16)f;
  return __builtin_bit_cast(u16, h);
}
__device__ __forceinline__ unsigned pk2h(float a, float b) {
  return __builtin_bit_cast(unsigned, __builtin_amdgcn_cvt_pkrtz(a, b));
}

__device__ __forceinline__ void async16(const void* g, void* l) {
  __builtin_amdgcn_global_load_lds(
      (const __attribute__((address_space(1))) unsigned int*)g,
      (__attribute__((address_space(3))) unsigned int*)l, 16, 0, 0);
}

#define MFMA_F16(a, b, c) __builtin_amdgcn_mfma_f32_16x16x32_f16((a), (b), (c), 0, 0, 0)

// ---------------- prep: cast x, Wqkv, Wp to fp16 ----------------
__global__ __launch_bounds__(256) void k_prep(const float* __restrict__ x,
                                              const float* __restrict__ Wqkv,
                                              const float* __restrict__ Wp,
                                              u16* __restrict__ xh,
                                              u16* __restrict__ wh,
                                              u16* __restrict__ wph) {
  const int blk = blockIdx.x, t = threadIdx.x;
  if (blk < 3072) {
    int i = blk * 256 + t;
    float4 v = ((const float4*)x)[i];
    ((ushort4*)xh)[i] = make_ushort4(f2h(v.x), f2h(v.y), f2h(v.z), f2h(v.w));
  } else if (blk < 4800) {
    int i = (blk - 3072) * 256 + t;
    float4 v = ((const float4*)Wqkv)[i];
    ((ushort4*)wh)[i] = make_ushort4(f2h(v.x), f2h(v.y), f2h(v.z), f2h(v.w));
  } else {
    int i = (blk - 4800) * 256 + t;
    float4 v = ((const float4*)Wp)[i];
    ((ushort4*)wph)[i] = make_ushort4(f2h(v.x), f2h(v.y), f2h(v.z), f2h(v.w));
  }
}

// ---------------- K1: qkv = x @ Wqkv^T, fp16 single-MFMA ----------------
// M=4096 N=2304 K=768; 1-D grid 576 with GROUP_M=8 swizzle.
// Q,K cols -> qkf[4096][1536]; V cols (n0>=1536) -> vbuf[4096][768].
__global__ __launch_bounds__(256) void k_qkv(const u16* __restrict__ Axh,
                                             const u16* __restrict__ Bwh,
                                             u16* __restrict__ qkf,
                                             u16* __restrict__ vbuf) {
  __shared__ u16 smem[16384];   // 32 KB: [0:4096)=As, [4096:8192)=Bs; whole = repack T
  u16* As = smem;
  u16* Bs = smem + 4096;
  const int t = threadIdx.x, lane = t & 63, wave = t >> 6;
  const int wm = wave >> 1, wn = wave & 1;
  const int quad = lane >> 4, l16 = lane & 15;
  // GROUP_M=8 swizzle: per-XCD one A-strip reused over all 18 n-blocks
  const int pid = blockIdx.x;
  const int group = pid / 144;              // 144 = 8 * 18
  const int rem = pid - group * 144;
  const int m0 = (group * 8 + (rem & 7)) * 128;
  const int n0 = (rem >> 3) * 128;
  const bool vblk = (n0 >= 1536);
  const int srow = t >> 2, sch = (t & 3) * 8;
  f32x4 acc[4][4];
#pragma unroll
  for (int i = 0; i < 4; ++i)
#pragma unroll
    for (int j = 0; j < 4; ++j) acc[i][j] = (f32x4){0.f, 0.f, 0.f, 0.f};
  for (int k0 = 0; k0 < 768; k0 += 32) {
    const size_t ga = (size_t)(m0 + srow) * 768 + k0 + sch;
    const size_t gb = (size_t)(n0 + srow) * 768 + k0 + sch;
    __syncthreads();
    async16(Axh + ga, &As[t * 8]);
    async16(Axh + ga + (size_t)64 * 768, &As[2048 + t * 8]);
    async16(Bwh + gb, &Bs[t * 8]);
    async16(Bwh + gb + (size_t)64 * 768, &Bs[2048 + t * 8]);
    __syncthreads();
    f16x8 af[4], bfr[4];
#pragma unroll
    for (int i = 0; i < 4; ++i) af[i] = *(const f16x8*)&As[(wm * 64 + i * 16 + l16) * 32 + quad * 8];
#pragma unroll
    for (int j = 0; j < 4; ++j) bfr[j] = *(const f16x8*)&Bs[(wn * 64 + j * 16 + l16) * 32 + quad * 8];
#pragma unroll
    for (int i = 0; i < 4; ++i)
#pragma unroll
      for (int j = 0; j < 4; ++j) acc[i][j] = MFMA_F16(af[i], bfr[j], acc[i][j]);
  }
  // epilogue: XOR-swizzled LDS repack (writes conflict-free), coalesced 16B stores
  __syncthreads();
  u16* T = smem;
#pragma unroll
  for (int i = 0; i < 4; ++i)
#pragma unroll
    for (int j = 0; j < 4; ++j)
#pragma unroll
      for (int r = 0; r < 4; ++r) {
        const int row = wm * 64 + i * 16 + quad * 4 + r;
        const int col = wn * 64 + j * 16 + l16;
        T[row * 128 + (col ^ ((row & 7) << 4))] = f2h(acc[i][j][r]);
      }
  __syncthreads();
  const int row = t >> 1, halfc = (t & 1) * 64;
  const int sw = (row & 7) << 4;
  u16* dst = vblk ? (vbuf + (size_t)(m0 + row) * 768 + (n0 - 1536) + halfc)
                  : (qkf + (size_t)(m0 + row) * 1536 + n0 + halfc);
#pragma unroll
  for (int c = 0; c < 64; c += 8)
    *(uint4*)(dst + c) = *(const uint4*)&T[row * 128 + ((halfc + c) ^ sw)];
}

// ---------------- K2: scores(fp16) = Q @ K^T per (b,h), single fp16 MFMA ----------------
__global__ __launch_bounds__(256) void k_qk(const u16* __restrict__ qkf,
                                            u16* __restrict__ scbuf) {
  __shared__ u16 smem[4][4096];   // [0]=A stage, [1]=B stage; all 4 = repack tile
  u16* As = smem[0]; u16* Bs = smem[1];
  const int t = threadIdx.x, lane = t & 63, wave = t >> 6;
  const int wm = wave >> 1, wn = wave & 1;
  const int quad = lane >> 4, l16 = lane & 15;
  const int bh = blockIdx.z, b = bh / 12, h = bh % 12;
  const int m0 = blockIdx.y * 128, n0 = blockIdx.x * 128;
  const int srow = t >> 2, sch = (t & 3) * 8;
  u16* C = scbuf + ((size_t)bh << 20);
  f32x4 acc[4][4];
#pragma unroll
  for (int i = 0; i < 4; ++i)
#pragma unroll
    for (int j = 0; j < 4; ++j) acc[i][j] = (f32x4){0.f, 0.f, 0.f, 0.f};
  for (int k0 = 0; k0 < 64; k0 += 32) {
    const size_t ga = (size_t)(b * 1024 + m0 + srow) * 1536 + h * 64 + k0 + sch;
    const size_t gb = (size_t)(b * 1024 + n0 + srow) * 1536 + 768 + h * 64 + k0 + sch;
    __syncthreads();
    async16(qkf + ga, &As[t * 8]);
    async16(qkf + ga + (size_t)64 * 1536, &As[2048 + t * 8]);
    async16(qkf + gb, &Bs[t * 8]);
    async16(qkf + gb + (size_t)64 * 1536, &Bs[2048 + t * 8]);
    __syncthreads();
    f16x8 af[4], bfr[4];
#pragma unroll
    for (int i = 0; i < 4; ++i) af[i] = *(const f16x8*)&As[(wm * 64 + i * 16 + l16) * 32 + quad * 8];
#pragma unroll
    for (int j = 0; j < 4; ++j) bfr[j] = *(const f16x8*)&Bs[(wn * 64 + j * 16 + l16) * 32 + quad * 8];
#pragma unroll
    for (int i = 0; i < 4; ++i)
#pragma unroll
      for (int j = 0; j < 4; ++j) acc[i][j] = MFMA_F16(af[i], bfr[j], acc[i][j]);
  }
  __syncthreads();
  u16* T = &smem[0][0];
#pragma unroll
  for (int i = 0; i < 4; ++i)
#pragma unroll
    for (int j = 0; j < 4; ++j)
#pragma unroll
      for (int r = 0; r < 4; ++r) {
        const int row = wm * 64 + i * 16 + quad * 4 + r;
        const int col = wn * 64 + j * 16 + l16;
        T[row * 128 + (col ^ ((row & 7) << 4))] = f2h(acc[i][j][r]);
      }
  __syncthreads();
  const int row = t >> 1, halfc = (t & 1) * 64;
  const int sw = (row & 7) << 4;
  u16* dst = C + (size_t)(m0 + row) * 1024 + n0 + halfc;
#pragma unroll
  for (int c = 0; c < 64; c += 8)
    *(uint4*)(dst + c) = *(const uint4*)&T[row * 128 + ((halfc + c) ^ sw)];
}

// ---------------- K3: mix1 -> constant-shift softmax -> mix2; fp16 in/out, in place ----------------
__global__ __launch_bounds__(256) void k_mix(u16* __restrict__ scbuf,
                                             const float* __restrict__ Wl,
                                             const float* __restrict__ bl,
                                             const float* __restrict__ Ww,
                                             const float* __restrict__ bw) {
  __shared__ float wl_s[144], ww_s[144], bl_s[12], bw_s[12];
  __shared__ float red[4][12];
  const int t = threadIdx.x, lane = t & 63, wave = t >> 6;
  const int bq = blockIdx.x, b = bq >> 10, q = bq & 1023;
  if (t < 144) { wl_s[t] = Wl[t]; ww_s[t] = Ww[t]; }
  if (t < 12)  { bl_s[t] = bl[t]; bw_s[t] = bw[t]; }
  const size_t rowbase = (((size_t)b * 12 * 1024 + q) << 10) + 4 * t;  // + h<<20
  f32x2 raw[12][2];
#pragma unroll
  for (int h = 0; h < 12; ++h) {
    const u16* p = scbuf + rowbase + ((size_t)h << 20);
    uint2 u = *(const uint2*)p;
    f16x2 a01 = __builtin_bit_cast(f16x2, u.x);
    f16x2 a23 = __builtin_bit_cast(f16x2, u.y);
    raw[h][0] = (f32x2){(float)a01.x, (float)a01.y};
    raw[h][1] = (f32x2){(float)a23.x, (float)a23.y};
  }
  __syncthreads();
  // mix1 (pk-fma), bias pre-shifted by -16 (constant-shift softmax)
  f32x2 lg[12][2];
#pragma unroll
  for (int g = 0; g < 12; ++g) {
    f32x2 a0 = {bl_s[g] - 16.f, bl_s[g] - 16.f}, a1 = a0;
#pragma unroll
    for (int h = 0; h < 12; ++h) {
      const float wv = wl_s[g * 12 + h];
      const f32x2 w = {wv, wv};
      a0 = __builtin_elementwise_fma(w, raw[h][0], a0);
      a1 = __builtin_elementwise_fma(w, raw[h][1], a1);
    }
    lg[g][0] = a0; lg[g][1] = a1;
  }
  // exp + row sum (no max pass: exp(l-16) safe, |logit| << 104)
  float sm[12];
#pragma unroll
  for (int g = 0; g < 12; ++g) {
    f32x2 e0, e1;
    e0.x = __expf(lg[g][0].x); e0.y = __expf(lg[g][0].y);
    e1.x = __expf(lg[g][1].x); e1.y = __expf(lg[g][1].y);
    lg[g][0] = e0; lg[g][1] = e1;
    f32x2 s2 = e0 + e1;
    sm[g] = s2.x + s2.y;
  }
#pragma unroll
  for (int off = 32; off > 0; off >>= 1)
#pragma unroll
    for (int g = 0; g < 12; ++g) sm[g] += __shfl_xor(sm[g], off);
  if (lane == 0) {
#pragma unroll
    for (int g = 0; g < 12; ++g) red[wave][g] = sm[g];
  }
  __syncthreads();
#pragma unroll
  for (int g = 0; g < 12; ++g) {
    const float inv = 1.0f / (red[0][g] + red[1][g] + red[2][g] + red[3][g]);
    const f32x2 iv = {inv, inv};
    lg[g][0] *= iv;
    lg[g][1] *= iv;
  }
  // mix2 (pk-fma) + fp16 pack stores, in place
#pragma unroll
  for (int g2 = 0; g2 < 12; ++g2) {
    f32x2 o0 = {bw_s[g2], bw_s[g2]}, o1 = o0;
#pragma unroll
    for (int h = 0; h < 12; ++h) {
      const float wv = ww_s[g2 * 12 + h];
      const f32x2 w = {wv, wv};
      o0 = __builtin_elementwise_fma(w, lg[h][0], o0);
      o1 = __builtin_elementwise_fma(w, lg[h][1], o1);
    }
    uint2 st = make_uint2(pk2h(o0.x, o0.y), pk2h(o1.x, o1.y));
    *(uint2*)(scbuf + rowbase + ((size_t)g2 << 20)) = st;
  }
}

// ---------------- K4: ctx = P(fp16) @ V(fp16) per (b,h); V transposed in-LDS ----------------
// M=1024 N=64 K=1024; BM=128; waves 2x2, each 64x32 (4x2 frags)
__global__ __launch_bounds__(256) void k_pv(const u16* __restrict__ probs,
                                            const u16* __restrict__ vbuf,
                                            u16* __restrict__ ctx) {
  __shared__ u16 As[4096];      // 128x32 P tile
  __shared__ u16 Bs[64 * 40];   // V^T tile: [e][s-chunk 32], row stride 40 (16B-aligned)
  const int t = threadIdx.x, lane = t & 63, wave = t >> 6;
  const int wm = wave >> 1, wn = wave & 1;
  const int quad = lane >> 4, l16 = lane & 15;
  const int bh = blockIdx.y, b = bh / 12, h = bh % 12;
  const int m0 = blockIdx.x * 128;
  const u16* P = probs + ((size_t)bh << 20);
  const int srow = t >> 2, sch = (t & 3) * 8;
  const int ev = t & 63, s8 = (t >> 6) * 8;   // V transpose-load: e=ev, s-chunk s8
  f32x4 acc[4][2];
#pragma unroll
  for (int i = 0; i < 4; ++i)
#pragma unroll
    for (int j = 0; j < 2; ++j) acc[i][j] = (f32x4){0.f, 0.f, 0.f, 0.f};
  for (int k0 = 0; k0 < 1024; k0 += 32) {
    const u16* vp = vbuf + (size_t)(b * 1024 + k0 + s8) * 768 + h * 64 + ev;
    u16 vcol[8];
#pragma unroll
    for (int i = 0; i < 8; ++i) vcol[i] = vp[(size_t)i * 768];
    __syncthreads();
    const u16* ga = P + (size_t)(m0 + srow) * 1024 + k0 + sch;
    async16(ga, &As[t * 8]);
    async16(ga + (size_t)64 * 1024, &As[2048 + t * 8]);
    *(ushort4*)&Bs[ev * 40 + s8] = make_ushort4(vcol[0], vcol[1], vcol[2], vcol[3]);
    *(ushort4*)&Bs[ev * 40 + s8 + 4] = make_ushort4(vcol[4], vcol[5], vcol[6], vcol[7]);
    __syncthreads();
    f16x8 af[4], bfr[2];
#pragma unroll
    for (int i = 0; i < 4; ++i) af[i] = *(const f16x8*)&As[(wm * 64 + i * 16 + l16) * 32 + quad * 8];
#pragma unroll
    for (int j = 0; j < 2; ++j) bfr[j] = *(const f16x8*)&Bs[(wn * 32 + j * 16 + l16) * 40 + quad * 8];
#pragma unroll
    for (int i = 0; i < 4; ++i)
#pragma unroll
      for (int j = 0; j < 2; ++j) acc[i][j] = MFMA_F16(af[i], bfr[j], acc[i][j]);
  }
#pragma unroll
  for (int i = 0; i < 4; ++i)
#pragma unroll
    for (int j = 0; j < 2; ++j)
#pragma unroll
      for (int r = 0; r < 4; ++r) {
        int q = m0 + wm * 64 + i * 16 + quad * 4 + r;
        int e = wn * 32 + j * 16 + l16;
        ctx[(size_t)(b * 1024 + q) * 768 + h * 64 + e] = f2h(acc[i][j][r]);
      }
}

// ---------------- K5: out = ctx @ Wp^T + bp (fp16 MFMA, fp32 out) ----------------
// M=4096 N=768 K=768
__global__ __launch_bounds__(256) void k_oproj(const u16* __restrict__ A,
                                               const u16* __restrict__ Bm,
                                               const float* __restrict__ bp,
                                               float* __restrict__ out) {
  __shared__ u16 As[4096];
  __shared__ u16 Bs[4096];
  const int t = threadIdx.x, lane = t & 63, wave = t >> 6;
  const int wm = wave >> 1, wn = wave & 1;
  const int quad = lane >> 4, l16 = lane & 15;
  const int m0 = blockIdx.y * 128, n0 = blockIdx.x * 128;
  const int srow = t >> 2, sch = (t & 3) * 8;
  f32x4 acc[4][4];
#pragma unroll
  for (int i = 0; i < 4; ++i)
#pragma unroll
    for (int j = 0; j < 4; ++j) acc[i][j] = (f32x4){0.f, 0.f, 0.f, 0.f};
  for (int k0 = 0; k0 < 768; k0 += 32) {
    __syncthreads();
    const u16* ga = A + (size_t)(m0 + srow) * 768 + k0 + sch;
    const u16* gb = Bm + (size_t)(n0 + srow) * 768 + k0 + sch;
    async16(ga, &As[t * 8]);
    async16(ga + (size_t)64 * 768, &As[2048 + t * 8]);
    async16(gb, &Bs[t * 8]);
    async16(gb + (size_t)64 * 768, &Bs[2048 + t * 8]);
    __syncthreads();
    f16x8 af[4], bfr[4];
#pragma unroll
    for (int i = 0; i < 4; ++i) af[i] = *(const f16x8*)&As[(wm * 64 + i * 16 + l16) * 32 + quad * 8];
#pragma unroll
    for (int j = 0; j < 4; ++j) bfr[j] = *(const f16x8*)&Bs[(wn * 64 + j * 16 + l16) * 32 + quad * 8];
#pragma unroll
    for (int i = 0; i < 4; ++i)
#pragma unroll
      for (int j = 0; j < 4; ++j) acc[i][j] = MFMA_F16(af[i], bfr[j], acc[i][j]);
  }
#pragma unroll
  for (int i = 0; i < 4; ++i)
#pragma unroll
    for (int j = 0; j < 4; ++j)
#pragma unroll
      for (int r = 0; r < 4; ++r) {
        const int row = m0 + wm * 64 + i * 16 + quad * 4 + r;
        const int col = n0 + wn * 64 + j * 16 + l16;
        out[(size_t)row * 768 + col] = acc[i][j][r] + bp[col];
      }
}

extern "C" void kernel_launch(void* const* d_in, const int* in_sizes, int n_in,
                              void* d_out, int out_size, void* d_ws, size_t ws_size,
                              hipStream_t stream) {
  const float* x    = (const float*)d_in[0];
  const float* Wqkv = (const float*)d_in[1];
  const float* Wl   = (const float*)d_in[2];
  const float* bl   = (const float*)d_in[3];
  const float* Ww   = (const float*)d_in[4];
  const float* bw   = (const float*)d_in[5];
  const float* Wp   = (const float*)d_in[6];
  const float* bp   = (const float*)d_in[7];
  float* out = (float*)d_out;

  char* ws = (char*)d_ws;
  u16* scbuf = (u16*)(ws + 0);               // 100,663,296 B
  u16* qkf   = (u16*)(ws + 100663296ull);    //  12,582,912 B
  u16* vbuf  = (u16*)(ws + 113246208ull);    //   6,291,456 B
  u16* ctx   = (u16*)(ws + 119537664ull);    //   6,291,456 B
  u16* x_h   = (u16*)(ws + 125829120ull);    //   6,291,456 B
  u16* wq_h  = (u16*)(ws + 132120576ull);    //   3,538,944 B
  u16* wp_h  = (u16*)(ws + 135659520ull);    //   1,179,648 B

  hipLaunchKernelGGL(k_prep, dim3(5376), dim3(256), 0, stream,
                     x, Wqkv, Wp, x_h, wq_h, wp_h);
  hipLaunchKernelGGL(k_qkv,  dim3(576),      dim3(256), 0, stream, x_h, wq_h, qkf, vbuf);
  hipLaunchKernelGGL(k_qk,   dim3(8, 8, 48), dim3(256), 0, stream, qkf, scbuf);
  hipLaunchKernelGGL(k_mix,  dim3(4096),     dim3(256), 0, stream, scbuf, Wl, bl, Ww, bw);
  hipLaunchKernelGGL(k_pv,   dim3(8, 48),    dim3(256), 0, stream, scbuf, vbuf, ctx);
  hipLaunchKernelGGL(k_oproj, dim3(6, 32),   dim3(256), 0, stream, ctx, wp_h, bp, out);
}